// Round 8
// baseline (4781.290 us; speedup 1.0000x reference)
//
#include <hip/hip_runtime.h>
#include <cmath>

// ---------------------------------------------------------------------------
// Tconv_35450660061268 — R11.
//   * logits_gemm3: LDS tile halved (sZ[128][68] 34.8KB -> sZ[64][68] 17.4KB,
//     K staged in two 64-row chunks) -> 4 -> 8 blocks/CU, lb(256,8).
//     R8-R10 showed dur pinned at 144-146us across FETCH 163->13.6MB:
//     latency-bound at 36% occupancy, not BW-bound. This doubles resident
//     waves to hide L2 latency.
//   * everything else unchanged from R10 (XCD swizzle kept: FT L2-resident).
// ---------------------------------------------------------------------------

namespace {

constexpr int H   = 128;
constexpr int KK  = 4;
constexpr int C   = 32;
constexpr int NE  = 40000;
constexpr int NR  = 256;
constexpr int T   = 4;
constexpr int E   = 100000;
constexpr int NT  = 1024;
constexpr int PIN = 388;     // H*KK - H + KK
constexpr int MW  = 1280;    // mask words per relation (padded; 1250 used)
constexpr int MWU = 1250;
constexpr int KC  = 4096;    // conv GEMM K (C*H)
constexpr int KSP = 32;      // conv split-K slices (K-slice = 128)
constexpr int MPE = 40192;   // NE padded to 256 (157*256)
constexpr size_t NEH = (size_t)NE * H;

__device__ __forceinline__ float sigm(float x) { return 1.0f / (1.0f + expf(-x)); }

// ---- row L2-normalize, one wave per row (init only) ------------------------
__global__ __launch_bounds__(256) void norm_rows(const float* __restrict__ in,
                                                 float* __restrict__ out, int n) {
  int row  = blockIdx.x * 4 + (threadIdx.x >> 6);
  int lane = threadIdx.x & 63;
  if (row >= n) return;
  const float2* ip = reinterpret_cast<const float2*>(in + (size_t)row * H);
  float2 v = ip[lane];
  float ss = v.x * v.x + v.y * v.y;
#pragma unroll
  for (int off = 32; off; off >>= 1) ss += __shfl_xor(ss, off);
  float inv = 1.0f / fmaxf(sqrtf(ss), 1e-12f);
  float2 o; o.x = v.x * inv; o.y = v.y * inv;
  reinterpret_cast<float2*>(out + (size_t)row * H)[lane] = o;
}

__global__ void copy_vec(const float* __restrict__ a, float* __restrict__ b, int n) {
  int i = blockIdx.x * blockDim.x + threadIdx.x;
  if (i < n) b[i] = a[i];
}

__global__ __launch_bounds__(256) void transpose128(const float* __restrict__ in,
                                                    float* __restrict__ out) {
  int i = blockIdx.x * 256 + threadIdx.x;   // grid 64
  int o = i >> 7, k = i & 127;
  out[k * H + o] = in[o * H + k];
}

// fwT[k*128 + o] = fw[o*4096 + k]   (128 x 4096 -> 4096 x 128), grid 2048
__global__ __launch_bounds__(256) void transposeFW(const float* __restrict__ in,
                                                   float* __restrict__ out) {
  int i = blockIdx.x * 256 + threadIdx.x;
  int o = i >> 12, k = i & 4095;
  out[(size_t)k * 128 + o] = in[i];
}

// tiled transpose: in[R][128] -> out[128][MP], grid MP/64 blocks.
// rows r >= R zero-filled.
__global__ __launch_bounds__(256) void transposeF(const float* __restrict__ in,
                                                  float* __restrict__ out,
                                                  int R, int MP) {
  __shared__ float tile[64][129];
  int r0 = blockIdx.x * 64;
  int t = threadIdx.x;
  for (int idx = t; idx < 64 * 128; idx += 256) {
    int q = idx >> 7, k = idx & 127;
    int r = r0 + q;
    tile[q][k] = (r < R) ? in[(size_t)r * H + k] : 0.0f;
  }
  __syncthreads();
  for (int idx = t; idx < 64 * 128; idx += 256) {
    int k = idx >> 6, q = idx & 63;
    out[(size_t)k * MP + r0 + q] = tile[q][k];
  }
}

// ---- mmt GRU pair + gated update + v = mmt_new @ tc_w^T + tc_b (1 block) ---
__global__ __launch_bounds__(128) void mmt_step(
    const float* __restrict__ mmt_in,
    const float* __restrict__ w1, const float* __restrict__ bi1, const float* __restrict__ bh1,
    const float* __restrict__ w2, const float* __restrict__ bi2, const float* __restrict__ bh2,
    const float* __restrict__ tcw, const float* __restrict__ tcb,
    float* __restrict__ mmt_out, float* __restrict__ vout) {
  __shared__ float sm[H], sm2[H];
  int t = threadIdx.x;
  sm[t] = mmt_in[t];
  __syncthreads();
  float g1r = bi1[t], g1z = bi1[H + t], g1n = bi1[2 * H + t];
  float g2r = bi2[t], g2z = bi2[H + t], g2n = bi2[2 * H + t];
  {
    const float4* r1p = reinterpret_cast<const float4*>(w1 + (size_t)t * H);
    const float4* z1p = reinterpret_cast<const float4*>(w1 + (size_t)(H + t) * H);
    const float4* n1p = reinterpret_cast<const float4*>(w1 + (size_t)(2 * H + t) * H);
    const float4* r2p = reinterpret_cast<const float4*>(w2 + (size_t)t * H);
    const float4* z2p = reinterpret_cast<const float4*>(w2 + (size_t)(H + t) * H);
    const float4* n2p = reinterpret_cast<const float4*>(w2 + (size_t)(2 * H + t) * H);
    const float4* x4 = reinterpret_cast<const float4*>(sm);
    for (int k = 0; k < 32; k++) {
      float4 x = x4[k];
      float4 a = r1p[k], b = z1p[k], c = n1p[k], d = r2p[k], e = z2p[k], f = n2p[k];
      g1r += x.x * a.x + x.y * a.y + x.z * a.z + x.w * a.w;
      g1z += x.x * b.x + x.y * b.y + x.z * b.z + x.w * b.w;
      g1n += x.x * c.x + x.y * c.y + x.z * c.z + x.w * c.w;
      g2r += x.x * d.x + x.y * d.y + x.z * d.z + x.w * d.w;
      g2z += x.x * e.x + x.y * e.y + x.z * e.z + x.w * e.w;
      g2n += x.x * f.x + x.y * f.y + x.z * f.z + x.w * f.w;
    }
  }
  float r1 = sigm(g1r + bh1[t]), z1 = sigm(g1z + bh1[H + t]);
  float n1 = tanhf(g1n + r1 * bh1[2 * H + t]);
  float nmmt = (1.0f - z1) * n1;
  float r2 = sigm(g2r + bh2[t]), z2 = sigm(g2z + bh2[H + t]);
  float n2 = tanhf(g2n + r2 * bh2[2 * H + t]);
  float gg = (1.0f - z2) * n2;
  float m  = sm[t];
  float mo = m + gg * (nmmt - m);
  mmt_out[t] = mo;
  sm2[t] = mo;
  __syncthreads();
  float v = tcb[t];
  {
    const float4* wp = reinterpret_cast<const float4*>(tcw + (size_t)t * H);
    const float4* x4 = reinterpret_cast<const float4*>(sm2);
    for (int k = 0; k < 32; k++) {
      float4 x = x4[k], w = wp[k];
      v += x.x * w.x + x.y * w.y + x.z * w.z + x.w * w.w;
    }
  }
  vout[t] = v;
}

// ---- build MT[p*H+o] = M[o][p] (k-major tconv map) -------------------------
__global__ __launch_bounds__(128) void build_M(const float* __restrict__ v,
                                               const float* __restrict__ pw,
                                               float* __restrict__ MT) {
  int o = blockIdx.x, p = threadIdx.x;
  __shared__ float sp[PIN];
  __shared__ float sv[H];
  for (int i = p; i < PIN; i += H) sp[i] = pw[(size_t)o * PIN + i];
  sv[p] = v[p];
  __syncthreads();
  float acc = 0.0f;
  int jlo = p - 31 > 0 ? p - 31 : 0;
  int jhi = p < 96 ? p : 96;
#pragma unroll
  for (int k = 0; k < KK; k++)
    for (int j = jlo; j <= jhi; j++) acc += sp[k * 97 + j] * sv[k * 32 + (p - j)];
  MT[p * H + o] = acc;
}

// ===========================================================================
// Register-tiled GEMM family (unchanged core from R2).
// ===========================================================================
__global__ __launch_bounds__(256) void gemm_bias(const float* __restrict__ X,
                                                 const float* __restrict__ WT,
                                                 const float* __restrict__ bias,
                                                 float* __restrict__ out) {
  __shared__ float sX[64 * H];
  int t = threadIdx.x;
  int base = blockIdx.x * 64;
  const float4* gx = reinterpret_cast<const float4*>(X + (size_t)base * H);
  float4* sx4 = reinterpret_cast<float4*>(sX);
#pragma unroll
  for (int i = 0; i < 8; i++) sx4[t + 256 * i] = gx[t + 256 * i];
  __syncthreads();
  int oq = (t & 31) * 4, ng = (t >> 5) * 8;
  float acc[8][4] = {};
  for (int k = 0; k < H; k += 4) {
    float4 w0 = *reinterpret_cast<const float4*>(&WT[(k + 0) * H + oq]);
    float4 w1 = *reinterpret_cast<const float4*>(&WT[(k + 1) * H + oq]);
    float4 w2 = *reinterpret_cast<const float4*>(&WT[(k + 2) * H + oq]);
    float4 w3 = *reinterpret_cast<const float4*>(&WT[(k + 3) * H + oq]);
#pragma unroll
    for (int m = 0; m < 8; m++) {
      float4 x = *reinterpret_cast<const float4*>(&sX[(ng + m) * H + k]);
      acc[m][0] += x.x * w0.x + x.y * w1.x + x.z * w2.x + x.w * w3.x;
      acc[m][1] += x.x * w0.y + x.y * w1.y + x.z * w2.y + x.w * w3.y;
      acc[m][2] += x.x * w0.z + x.y * w1.z + x.z * w2.z + x.w * w3.z;
      acc[m][3] += x.x * w0.w + x.y * w1.w + x.z * w2.w + x.w * w3.w;
    }
  }
  float4 b4 = *reinterpret_cast<const float4*>(&bias[oq]);
#pragma unroll
  for (int m = 0; m < 8; m++) {
    float4 o4 = {acc[m][0] + b4.x, acc[m][1] + b4.y, acc[m][2] + b4.z, acc[m][3] + b4.w};
    *reinterpret_cast<float4*>(&out[(size_t)(base + ng + m) * H + oq]) = o4;
  }
}

// RGCN layer fused: out = relu((A@wn)*inv_deg + Hm@ws + b); optional row-norm.
__global__ __launch_bounds__(256) void gemm_rgcn(const float* __restrict__ A,
                                                 const float* __restrict__ Hm,
                                                 const float* __restrict__ wn,
                                                 const float* __restrict__ ws,
                                                 const float* __restrict__ bias,
                                                 const int* __restrict__ deg,
                                                 float* __restrict__ out,
                                                 int donorm) {
  __shared__ float sA[32 * H];
  __shared__ float sH[32 * H];
  int t = threadIdx.x;
  int base = blockIdx.x * 32;
  const float4* ga = reinterpret_cast<const float4*>(A + (size_t)base * H);
  const float4* gh = reinterpret_cast<const float4*>(Hm + (size_t)base * H);
  float4* sa4 = reinterpret_cast<float4*>(sA);
  float4* sh4 = reinterpret_cast<float4*>(sH);
#pragma unroll
  for (int i = 0; i < 4; i++) { sa4[t + 256 * i] = ga[t + 256 * i]; sh4[t + 256 * i] = gh[t + 256 * i]; }
  __syncthreads();
  int oq = (t & 31) * 4, ng = (t >> 5) * 4;
  float accA[4][4] = {}, accS[4][4] = {};
  for (int k = 0; k < H; k += 4) {
    float4 n0 = *reinterpret_cast<const float4*>(&wn[(k + 0) * H + oq]);
    float4 n1 = *reinterpret_cast<const float4*>(&wn[(k + 1) * H + oq]);
    float4 n2 = *reinterpret_cast<const float4*>(&wn[(k + 2) * H + oq]);
    float4 n3 = *reinterpret_cast<const float4*>(&wn[(k + 3) * H + oq]);
    float4 s0 = *reinterpret_cast<const float4*>(&ws[(k + 0) * H + oq]);
    float4 s1 = *reinterpret_cast<const float4*>(&ws[(k + 1) * H + oq]);
    float4 s2 = *reinterpret_cast<const float4*>(&ws[(k + 2) * H + oq]);
    float4 s3 = *reinterpret_cast<const float4*>(&ws[(k + 3) * H + oq]);
#pragma unroll
    for (int m = 0; m < 4; m++) {
      float4 a = *reinterpret_cast<const float4*>(&sA[(ng + m) * H + k]);
      float4 h = *reinterpret_cast<const float4*>(&sH[(ng + m) * H + k]);
      accA[m][0] += a.x * n0.x + a.y * n1.x + a.z * n2.x + a.w * n3.x;
      accA[m][1] += a.x * n0.y + a.y * n1.y + a.z * n2.y + a.w * n3.y;
      accA[m][2] += a.x * n0.z + a.y * n1.z + a.z * n2.z + a.w * n3.z;
      accA[m][3] += a.x * n0.w + a.y * n1.w + a.z * n2.w + a.w * n3.w;
      accS[m][0] += h.x * s0.x + h.y * s1.x + h.z * s2.x + h.w * s3.x;
      accS[m][1] += h.x * s0.y + h.y * s1.y + h.z * s2.y + h.w * s3.y;
      accS[m][2] += h.x * s0.z + h.y * s1.z + h.z * s2.z + h.w * s3.z;
      accS[m][3] += h.x * s0.w + h.y * s1.w + h.z * s2.w + h.w * s3.w;
    }
  }
  float4 b4 = *reinterpret_cast<const float4*>(&bias[oq]);
  float v[4][4];
#pragma unroll
  for (int m = 0; m < 4; m++) {
    float inv = 1.0f / fmaxf((float)deg[base + ng + m], 1.0f);
    v[m][0] = fmaxf(accA[m][0] * inv + accS[m][0] + b4.x, 0.0f);
    v[m][1] = fmaxf(accA[m][1] * inv + accS[m][1] + b4.y, 0.0f);
    v[m][2] = fmaxf(accA[m][2] * inv + accS[m][2] + b4.z, 0.0f);
    v[m][3] = fmaxf(accA[m][3] * inv + accS[m][3] + b4.w, 0.0f);
  }
  if (donorm) {
#pragma unroll
    for (int m = 0; m < 4; m++) {
      float ss = v[m][0]*v[m][0] + v[m][1]*v[m][1] + v[m][2]*v[m][2] + v[m][3]*v[m][3];
#pragma unroll
      for (int off = 16; off; off >>= 1) ss += __shfl_xor(ss, off);
      float inv = 1.0f / fmaxf(sqrtf(ss), 1e-12f);
      v[m][0] *= inv; v[m][1] *= inv; v[m][2] *= inv; v[m][3] *= inv;
    }
  }
#pragma unroll
  for (int m = 0; m < 4; m++) {
    float4 o4 = {v[m][0], v[m][1], v[m][2], v[m][3]};
    *reinterpret_cast<float4*>(&out[(size_t)(base + ng + m) * H + oq]) = o4;
  }
}

// out = e + sigm(e@WT+b)*(nf - e)
__global__ __launch_bounds__(256) void gemm_update(const float* __restrict__ Xe,
                                                   const float* __restrict__ WT,
                                                   const float* __restrict__ bias,
                                                   const float* __restrict__ nf,
                                                   float* __restrict__ out) {
  __shared__ float sX[64 * H];
  int t = threadIdx.x;
  int base = blockIdx.x * 64;
  const float4* gx = reinterpret_cast<const float4*>(Xe + (size_t)base * H);
  float4* sx4 = reinterpret_cast<float4*>(sX);
#pragma unroll
  for (int i = 0; i < 8; i++) sx4[t + 256 * i] = gx[t + 256 * i];
  __syncthreads();
  int oq = (t & 31) * 4, ng = (t >> 5) * 8;
  float acc[8][4] = {};
  for (int k = 0; k < H; k += 4) {
    float4 w0 = *reinterpret_cast<const float4*>(&WT[(k + 0) * H + oq]);
    float4 w1 = *reinterpret_cast<const float4*>(&WT[(k + 1) * H + oq]);
    float4 w2 = *reinterpret_cast<const float4*>(&WT[(k + 2) * H + oq]);
    float4 w3 = *reinterpret_cast<const float4*>(&WT[(k + 3) * H + oq]);
#pragma unroll
    for (int m = 0; m < 8; m++) {
      float4 x = *reinterpret_cast<const float4*>(&sX[(ng + m) * H + k]);
      acc[m][0] += x.x * w0.x + x.y * w1.x + x.z * w2.x + x.w * w3.x;
      acc[m][1] += x.x * w0.y + x.y * w1.y + x.z * w2.y + x.w * w3.y;
      acc[m][2] += x.x * w0.z + x.y * w1.z + x.z * w2.z + x.w * w3.z;
      acc[m][3] += x.x * w0.w + x.y * w1.w + x.z * w2.w + x.w * w3.w;
    }
  }
  float4 b4 = *reinterpret_cast<const float4*>(&bias[oq]);
#pragma unroll
  for (int m = 0; m < 8; m++) {
    size_t row = (size_t)(base + ng + m) * H;
    float4 e4 = *reinterpret_cast<const float4*>(&sX[(ng + m) * H + oq]);
    float4 f4 = *reinterpret_cast<const float4*>(&nf[row + oq]);
    float4 o4 = {e4.x + sigm(acc[m][0] + b4.x) * (f4.x - e4.x),
                 e4.y + sigm(acc[m][1] + b4.y) * (f4.y - e4.y),
                 e4.z + sigm(acc[m][2] + b4.z) * (f4.z - e4.z),
                 e4.w + sigm(acc[m][3] + b4.w) * (f4.w - e4.w)};
    *reinterpret_cast<float4*>(&out[row + oq]) = o4;
  }
}

// ===========================================================================
// Edge prep: rel-bitmask scatter + dst-degree histogram in one pass over E.
// ===========================================================================
__global__ __launch_bounds__(256) void edge_prep(const int* __restrict__ s,
                                                 const int* __restrict__ d,
                                                 const int* __restrict__ r,
                                                 unsigned int* __restrict__ mask,
                                                 int* __restrict__ deg) {
  int e = blockIdx.x * 256 + threadIdx.x;
  if (e >= E) return;
  int ri = r[e], si = s[e], di = d[e];
  atomicOr(&mask[(size_t)ri * MW + (si >> 5)], 1u << (si & 31));
  atomicOr(&mask[(size_t)ri * MW + (di >> 5)], 1u << (di & 31));
  atomicAdd(&deg[di], 1);
}

// wave-shfl scan over deg -> rowptr (exclusive) + wpos copy
__global__ __launch_bounds__(1024) void scan_deg(const int* __restrict__ deg,
                                                 int* __restrict__ rowptr,
                                                 int* __restrict__ wpos) {
  __shared__ int wsum[16];
  __shared__ int carry_s;
  int tid = threadIdx.x, lane = tid & 63, w = tid >> 6;
  if (tid == 0) carry_s = 0;
  __syncthreads();
  for (int base = 0; base < NE; base += 1024) {
    int idx = base + tid;
    int v = idx < NE ? deg[idx] : 0;
    int x = v;
#pragma unroll
    for (int off = 1; off < 64; off <<= 1) {
      int y = __shfl_up(x, off, 64);
      if (lane >= off) x += y;
    }
    if (lane == 63) wsum[w] = x;
    __syncthreads();
    int carry = carry_s;
    int wpre = 0;
    for (int i = 0; i < w; i++) wpre += wsum[i];
    int excl = carry + wpre + x - v;
    if (idx < NE) { rowptr[idx] = excl; wpos[idx] = excl; }
    __syncthreads();
    if (tid == 1023) carry_s = carry + wpre + x;
  }
  __syncthreads();
  if (tid == 0) rowptr[NE] = carry_s;
}

__global__ __launch_bounds__(256) void edge_fill(const int* __restrict__ d,
                                                 int* __restrict__ wpos,
                                                 int* __restrict__ elist) {
  int e = blockIdx.x * 256 + threadIdx.x;
  if (e >= E) return;
  int p = atomicAdd(&wpos[d[e]], 1);
  elist[p] = e;
}

// agg[n][dim] = sum_{e: d[e]==n} h[s[e]][dim] + ef[r[e]][dim]   (2 nodes/blk)
__global__ __launch_bounds__(256) void rgcn_gather(const float* __restrict__ h,
                                                   const float* __restrict__ ef,
                                                   const int* __restrict__ rowptr,
                                                   const int* __restrict__ elist,
                                                   const int* __restrict__ s,
                                                   const int* __restrict__ r,
                                                   float* __restrict__ agg) {
  int node = blockIdx.x * 2 + (threadIdx.x >> 7);
  int dim  = threadIdx.x & 127;
  int b = rowptr[node], e2 = rowptr[node + 1];
  float acc = 0.0f;
  for (int i = b; i < e2; i++) {
    int e = elist[i];
    acc += h[(size_t)s[e] * H + dim] + ef[(size_t)r[e] * H + dim];
  }
  agg[(size_t)node * H + dim] = acc;
}

// ---- _agg_rel masked sum: 32 partitions per relation -----------------------
__global__ __launch_bounds__(128) void agg_rel_sum(const unsigned int* __restrict__ mask,
                                                   const float* __restrict__ ent,
                                                   float* __restrict__ rsum,
                                                   float* __restrict__ rcnt) {
  int rel = blockIdx.x, part = blockIdx.y, tid = threadIdx.x;
  const int WPS = (MWU + 31) / 32;  // 40
  int w0 = part * WPS;
  int w1 = w0 + WPS < MWU ? w0 + WPS : MWU;
  float acc = 0.0f, cnt = 0.0f;
  const unsigned int* mrow = mask + (size_t)rel * MW;
  for (int w = w0; w < w1; w++) {
    unsigned int bits = mrow[w];
    if (!bits) continue;
    cnt += (float)__popc(bits);
    int base = w << 5;
    while (bits) {
      int b = __ffs(bits) - 1;
      bits &= bits - 1;
      acc += ent[(size_t)(base + b) * H + tid];
    }
  }
  if (acc != 0.0f) atomicAdd(&rsum[rel * H + tid], acc);
  if (tid == 0 && cnt != 0.0f) atomicAdd(&rcnt[rel], cnt);
}

// ---- relation GRU (finalize fused) + row normalize -------------------------
__global__ __launch_bounds__(128) void rel_gru(const float* __restrict__ rsum,
                                               const float* __restrict__ rcnt,
                                               const float* __restrict__ rel_param,
                                               const float* __restrict__ relh,
                                               const float* __restrict__ wih,
                                               const float* __restrict__ whh,
                                               const float* __restrict__ bih,
                                               const float* __restrict__ bhh,
                                               float* __restrict__ outp) {
  int rel = blockIdx.x, tid = threadIdx.x;
  __shared__ float sx[2 * H], sh[H], red[H];
  float c = rcnt[rel];
  sx[tid]     = c > 0.0f ? rsum[rel * H + tid] / fmaxf(c, 1.0f) : 0.0f;
  sx[H + tid] = rel_param[rel * H + tid];
  sh[tid]     = relh[rel * H + tid];
  __syncthreads();
  float gr = bih[tid], gz = bih[H + tid], gn = bih[2 * H + tid];
  {
    const float4* rp = reinterpret_cast<const float4*>(wih + (size_t)tid * 2 * H);
    const float4* zp = reinterpret_cast<const float4*>(wih + (size_t)(H + tid) * 2 * H);
    const float4* np = reinterpret_cast<const float4*>(wih + (size_t)(2 * H + tid) * 2 * H);
    const float4* x4 = reinterpret_cast<const float4*>(sx);
    for (int k = 0; k < 64; k++) {
      float4 x = x4[k];
      float4 a = rp[k], b = zp[k], cc = np[k];
      gr += x.x * a.x + x.y * a.y + x.z * a.z + x.w * a.w;
      gz += x.x * b.x + x.y * b.y + x.z * b.z + x.w * b.w;
      gn += x.x * cc.x + x.y * cc.y + x.z * cc.z + x.w * cc.w;
    }
  }
  float hr = bhh[tid], hz = bhh[H + tid], hn = bhh[2 * H + tid];
  {
    const float4* rp = reinterpret_cast<const float4*>(whh + (size_t)tid * H);
    const float4* zp = reinterpret_cast<const float4*>(whh + (size_t)(H + tid) * H);
    const float4* np = reinterpret_cast<const float4*>(whh + (size_t)(2 * H + tid) * H);
    const float4* h4 = reinterpret_cast<const float4*>(sh);
    for (int k = 0; k < 32; k++) {
      float4 x = h4[k];
      float4 a = rp[k], b = zp[k], cc = np[k];
      hr += x.x * a.x + x.y * a.y + x.z * a.z + x.w * a.w;
      hz += x.x * b.x + x.y * b.y + x.z * b.z + x.w * b.w;
      hn += x.x * cc.x + x.y * cc.y + x.z * cc.z + x.w * cc.w;
    }
  }
  float r = sigm(gr + hr), z = sigm(gz + hz), nn = tanhf(gn + r * hn);
  float val = (1.0f - z) * nn + z * sh[tid];
  red[tid] = val * val;
  __syncthreads();
  for (int s2 = 64; s2 > 0; s2 >>= 1) {
    if (tid < s2) red[tid] += red[tid + s2];
    __syncthreads();
  }
  float inv = 1.0f / fmaxf(sqrtf(red[0]), 1e-12f);
  outp[rel * H + tid] = val * inv;
}

// ===========================================================================
// ConvTransE front — stage A: materialize Y[NT][4096] = relu(conv(x)).
// ===========================================================================
__global__ __launch_bounds__(256) void conv_relu(const float* __restrict__ fa,
                                                 const int* __restrict__ ia,
                                                 const float* __restrict__ fbm,
                                                 const int* __restrict__ ib,
                                                 const float* __restrict__ ck,
                                                 const float* __restrict__ ckb,
                                                 float* __restrict__ Y) {
  __shared__ float sx[8 * 2 * H];   // 8 KB
  __shared__ float sck[C * 6];
  __shared__ float sckb[C];
  int tid = threadIdx.x, q0 = blockIdx.x * 8;
  if (tid < C * 6) sck[tid] = ck[tid];
  if (tid < C)     sckb[tid] = ckb[tid];
#pragma unroll
  for (int i = tid; i < 2048; i += 256) {
    int q = i >> 8, half = (i >> 7) & 1, p = i & 127;
    int node = (half ? ib : ia)[q0 + q];
    sx[i] = (half ? fbm : fa)[(size_t)node * H + p];
  }
  __syncthreads();
  for (int i4 = tid; i4 < 8192; i4 += 256) {
    int q = i4 >> 10, rr = i4 & 1023;
    int c = rr >> 5, p0 = (rr & 31) << 2;
    const float* x0 = &sx[q * 256];
    const float* x1 = x0 + 128;
    float k00 = sck[c * 6 + 0], k01 = sck[c * 6 + 1], k02 = sck[c * 6 + 2];
    float k10 = sck[c * 6 + 3], k11 = sck[c * 6 + 4], k12 = sck[c * 6 + 5];
    float bb = sckb[c];
    float4 o;
    float* op = &o.x;
#pragma unroll
    for (int dd = 0; dd < 4; dd++) {
      int p = p0 + dd;
      float acc = bb + x0[p] * k01 + x1[p] * k11;
      if (p - 1 >= 0)  acc += x0[p - 1] * k00 + x1[p - 1] * k10;
      if (p + 1 < H)   acc += x0[p + 1] * k02 + x1[p + 1] * k12;
      op[dd] = fmaxf(acc, 0.0f);
    }
    *reinterpret_cast<float4*>(&Y[(size_t)(q0 + q) * KC + rr * 4]) = o;
  }
}

// ===========================================================================
// ConvTransE front — stage B: split-K GEMM, Zp[ks] = Y[:,ksl] @ fwT[ksl,:].
// ===========================================================================
__global__ __launch_bounds__(256) void conv_gemm(const float* __restrict__ Y,
                                                 const float* __restrict__ fwT,
                                                 float* __restrict__ Zp) {
  int t = threadIdx.x;
  int mb = blockIdx.x * 32, ks = blockIdx.y;
  int oq = (t & 31) * 4, ng = (t >> 5) * 4;
  const float* yb = Y + (size_t)(mb + ng) * KC + ks * 128;
  const float* wb = fwT + (size_t)ks * 128 * H + oq;
  float acc[4][4] = {};
  for (int k = 0; k < 128; k += 4) {
    float4 w0 = *reinterpret_cast<const float4*>(wb + (size_t)(k + 0) * H);
    float4 w1 = *reinterpret_cast<const float4*>(wb + (size_t)(k + 1) * H);
    float4 w2 = *reinterpret_cast<const float4*>(wb + (size_t)(k + 2) * H);
    float4 w3 = *reinterpret_cast<const float4*>(wb + (size_t)(k + 3) * H);
#pragma unroll
    for (int m = 0; m < 4; m++) {
      float4 y = *reinterpret_cast<const float4*>(yb + (size_t)m * KC + k);
      acc[m][0] += y.x * w0.x + y.y * w1.x + y.z * w2.x + y.w * w3.x;
      acc[m][1] += y.x * w0.y + y.y * w1.y + y.z * w2.y + y.w * w3.y;
      acc[m][2] += y.x * w0.z + y.y * w1.z + y.z * w2.z + y.w * w3.z;
      acc[m][3] += y.x * w0.w + y.y * w1.w + y.z * w2.w + y.w * w3.w;
    }
  }
  float* zb = Zp + (size_t)ks * NT * H;
#pragma unroll
  for (int m = 0; m < 4; m++) {
    float4 o4 = {acc[m][0], acc[m][1], acc[m][2], acc[m][3]};
    *reinterpret_cast<float4*>(&zb[(size_t)(mb + ng + m) * H + oq]) = o4;
  }
}

__global__ __launch_bounds__(256) void conv_finalize(const float* __restrict__ Zp,
                                                     const float* __restrict__ fb,
                                                     float* __restrict__ Z) {
  int i = blockIdx.x * 256 + threadIdx.x;  // NT*H / 256
  int o = i & 127;
  float v = fb[o];
#pragma unroll
  for (int s = 0; s < KSP; s++) v += Zp[(size_t)s * NT * H + i];
  Z[i] = fmaxf(v, 0.0f);
}

// ===========================================================================
// logits GEMM v4: out[q][m] = sum_k Z[q][k] * FT[k][m].
// XCD swizzle (FT L2-resident) + K staged in two 64-row LDS chunks
// (17.4KB -> 8 blocks/CU, lb(256,8)) to hide L2 latency.
// ===========================================================================
__global__ __launch_bounds__(256, 8) void logits_gemm3(const float* __restrict__ Z,
                                                       const float* __restrict__ FT,
                                                       float* __restrict__ out,
                                                       int M, int MP, int nmt, int swiz) {
  __shared__ float sZ[64][68];
  int t = threadIdx.x;
  int bq, bm;
  if (swiz) {
    int id = blockIdx.x;
    int xcd = id & 7, w = id >> 3;
    int mt = (w >> 4) * 8 + xcd, j = w & 15;
    if (mt >= nmt) return;
    bq = j * 64; bm = mt * 256;
  } else {
    bq = blockIdx.x * 64; bm = blockIdx.y * 256;
  }
  int tx = t & 31, ty = t >> 5;
  int m0 = bm + tx * 8, q0 = ty * 8;
  const float* ftp = FT + m0;
  float acc[8][8] = {};
  for (int kc = 0; kc < H; kc += 64) {
    __syncthreads();
    for (int idx = t; idx < 64 * 64; idx += 256) {
      int q = idx >> 6, k = idx & 63;
      sZ[k][q] = Z[(size_t)(bq + q) * H + kc + k];
    }
    __syncthreads();
#pragma unroll 2
    for (int k = 0; k < 64; k++) {
      float4 fa = *reinterpret_cast<const float4*>(ftp + (size_t)(kc + k) * MP);
      float4 fb = *reinterpret_cast<const float4*>(ftp + (size_t)(kc + k) * MP + 4);
      float4 za = *reinterpret_cast<const float4*>(&sZ[k][q0]);
      float4 zb = *reinterpret_cast<const float4*>(&sZ[k][q0 + 4]);
      float zq[8] = {za.x, za.y, za.z, za.w, zb.x, zb.y, zb.z, zb.w};
      float fm[8] = {fa.x, fa.y, fa.z, fa.w, fb.x, fb.y, fb.z, fb.w};
#pragma unroll
      for (int i = 0; i < 8; i++)
#pragma unroll
        for (int j = 0; j < 8; j++) acc[i][j] += zq[i] * fm[j];
    }
  }
  if (m0 >= M) return;
#pragma unroll
  for (int i = 0; i < 8; i++) {
    size_t row = (size_t)(bq + q0 + i) * (size_t)M + m0;
    float4 o1 = {acc[i][0], acc[i][1], acc[i][2], acc[i][3]};
    float4 o2 = {acc[i][4], acc[i][5], acc[i][6], acc[i][7]};
    *reinterpret_cast<float4*>(&out[row]) = o1;
    *reinterpret_cast<float4*>(&out[row + 4]) = o2;
  }
}

}  // namespace

extern "C" void kernel_launch(void* const* d_in, const int* in_sizes, int n_in,
                              void* d_out, int out_size, void* d_ws, size_t ws_size,
                              hipStream_t stream) {
  (void)in_sizes; (void)n_in; (void)out_size; (void)ws_size;
  const float* ent_embeds = (const float*)d_in[0];
  const float* rel_embeds = (const float*)d_in[1];
  const float* mmt_embed  = (const float*)d_in[2];
  const float* tc_w  = (const float*)d_in[3];
  const float* tc_b  = (const float*)d_in[4];
  const float* tc_pw = (const float*)d_in[5];
  const float* tc_pb = (const float*)d_in[6];
  const float* g1_wih = (const float*)d_in[7];
  const float* g1_whh = (const float*)d_in[8];
  const float* g1_bih = (const float*)d_in[9];
  const float* g1_bhh = (const float*)d_in[10];
  const float* l1_wih = (const float*)d_in[11];
  const float* l1_bih = (const float*)d_in[13];
  const float* l1_bhh = (const float*)d_in[14];
  const float* l2_wih = (const float*)d_in[15];
  const float* l2_bih = (const float*)d_in[17];
  const float* l2_bhh = (const float*)d_in[18];
  const float* lin_w = (const float*)d_in[19];
  const float* lin_b = (const float*)d_in[20];
  const float* rgcn_wn = (const float*)d_in[21];
  const float* rgcn_ws = (const float*)d_in[22];
  const float* rgcn_b  = (const float*)d_in[23];
  const float* oc_k  = (const float*)d_in[24];
  const float* oc_kb = (const float*)d_in[25];
  const float* oc_fw = (const float*)d_in[26];
  const float* oc_fb = (const float*)d_in[27];
  const float* rc_k  = (const float*)d_in[28];
  const float* rc_kb = (const float*)d_in[29];
  const float* rc_fw = (const float*)d_in[30];
  const float* rc_fb = (const float*)d_in[31];
  const int* src  = (const int*)d_in[32];
  const int* dst  = (const int*)d_in[33];
  const int* rid  = (const int*)d_in[34];
  const int* qsub = (const int*)d_in[35];
  const int* qrel = (const int*)d_in[36];
  const int* qobj = (const int*)d_in[37];

  float* out = (float*)d_out;
  float* ws  = (float*)d_ws;

  // ---- d_ws layout (floats) ----
  size_t off = 0;
  float* relhB[3] = {ws + off, ws + off + (size_t)NR * H, ws + off + 2 * (size_t)NR * H};
  off += 3 * (size_t)NR * H;
  float* rel_sum = ws + off; off += (size_t)NR * H;
  float* rcnt    = ws + off; off += NR;
  float* mmtbuf0 = ws + off; off += H;
  float* mmtbuf1 = ws + off; off += H;
  float* vbuf    = ws + off; off += H;
  float* MT      = ws + off; off += (size_t)H * H;
  float* WTlin   = ws + off; off += (size_t)H * H;
  float* Zo      = ws + off; off += (size_t)NT * H;
  float* Zr      = ws + off; off += (size_t)NT * H;
  float* FTe     = ws + off; off += (size_t)H * MPE;    // 5.14M floats
  float* FTr     = ws + off; off += (size_t)H * NR;
  unsigned int* mask = (unsigned int*)(ws + off); off += (size_t)NR * MW;

  // ---- d_out as scratch: 4 rotating NE*H buffers + CSR ints in the tail ----
  float* B[4] = {out, out + NEH, out + 2 * NEH, out + 3 * NEH};
  int* itail   = (int*)(out + 4 * NEH);
  int* deg     = itail;
  int* rowptr  = itail + NE;
  int* wpos    = itail + 2 * NE + 1;
  int* elist   = itail + 3 * NE + 1;
  float* mmtb[2] = {mmtbuf0, mmtbuf1};
  // conv scratch (dead before logits write out). All below 10.24M floats;
  // final entities end up in B[2] = [10.24M, 15.36M) — no overlap.
  float* Ybuf  = out;                                     // [0, 4.19M)
  float* Zp    = out + (size_t)NT * KC;                   // [4.19M, 8.39M)
  float* fwTo  = Zp + (size_t)KSP * NT * H;               // [8.39M, 8.91M)
  float* fwTr  = fwTo + (size_t)KC * H;                   // [8.91M, 9.44M)

  norm_rows<<<(NE + 3) / 4, 256, 0, stream>>>(ent_embeds, B[0], NE);
  norm_rows<<<(NR + 3) / 4, 256, 0, stream>>>(rel_embeds, relhB[0], NR);
  copy_vec<<<1, 128, 0, stream>>>(mmt_embed, mmtbuf0, H);
  transpose128<<<64, 256, 0, stream>>>(lin_w, WTlin);

  int cur = 0, curRelh = 0;
  for (int t = 0; t < T; t++) {
    int fr[3], fi = 0;
    for (int b = 0; b < 4; b++) if (b != cur) fr[fi++] = b;
    int bX = fr[0], bG = fr[1], bY = fr[2];
    const int* s_t = src + (size_t)t * E;
    const int* d_t = dst + (size_t)t * E;
    const int* r_t = rid + (size_t)t * E;

    mmt_step<<<1, 128, 0, stream>>>(mmtb[t & 1], l1_wih, l1_bih, l1_bhh,
                                    l2_wih, l2_bih, l2_bhh, tc_w, tc_b,
                                    mmtb[(t + 1) & 1], vbuf);
    build_M<<<H, H, 0, stream>>>(vbuf, tc_pw, MT);
    gemm_bias<<<NE / 64, 256, 0, stream>>>(B[cur], MT, tc_pb, B[bX]);
    gemm_bias<<<NR / 64, 256, 0, stream>>>(relhB[curRelh], MT, tc_pb, relhB[2]);

    // edge prep: rel bitmask + dst degree (one pass)
    hipMemsetAsync(mask, 0, (size_t)NR * MW * 4, stream);
    hipMemsetAsync(deg, 0, (size_t)NE * 4, stream);
    edge_prep<<<(E + 255) / 256, 256, 0, stream>>>(s_t, d_t, r_t, mask, deg);

    hipMemsetAsync(rel_sum, 0, ((size_t)NR * H + NR) * 4, stream);
    agg_rel_sum<<<dim3(NR, 32), 128, 0, stream>>>(mask, B[bX], rel_sum, rcnt);
    int nextRelh = 1 - curRelh;
    rel_gru<<<NR, 128, 0, stream>>>(rel_sum, rcnt, rel_embeds, relhB[2],
                                    g1_wih, g1_whh, g1_bih, g1_bhh, relhB[nextRelh]);

    scan_deg<<<1, 1024, 0, stream>>>(deg, rowptr, wpos);
    edge_fill<<<(E + 255) / 256, 256, 0, stream>>>(d_t, wpos, elist);

    // RGCN layer 0
    rgcn_gather<<<NE / 2, 256, 0, stream>>>(B[bX], relhB[nextRelh], rowptr, elist, s_t, r_t, B[bG]);
    gemm_rgcn<<<NE / 32, 256, 0, stream>>>(B[bG], B[bX], rgcn_wn, rgcn_ws, rgcn_b, deg, B[bY], 0);
    // RGCN layer 1 (+ fused row-normalize)
    rgcn_gather<<<NE / 2, 256, 0, stream>>>(B[bY], relhB[nextRelh], rowptr, elist, s_t, r_t, B[bG]);
    gemm_rgcn<<<NE / 32, 256, 0, stream>>>(B[bG], B[bY], rgcn_wn + H * H, rgcn_ws + H * H,
                                           rgcn_b + H, deg, B[cur], 1);

    gemm_update<<<NE / 64, 256, 0, stream>>>(B[bX], WTlin, lin_b, B[cur], B[bY]);

    cur = bY;
    curRelh = nextRelh;
  }

  float* entF  = B[cur];           // final entities live in d_out scratch
  float* relhF = relhB[curRelh];

  // transpose finals for the logits GEMM (FT[k][m]); pad rows zero-filled
  transposeF<<<MPE / 64, 256, 0, stream>>>(entF, FTe, NE, MPE);
  transposeF<<<NR / 64, 256, 0, stream>>>(relhF, FTr, NR, NR);

  // ConvTransE fronts: transpose weights, materialize Y, coalesced split-K GEMM
  transposeFW<<<2048, 256, 0, stream>>>(oc_fw, fwTo);
  transposeFW<<<2048, 256, 0, stream>>>(rc_fw, fwTr);

  conv_relu<<<NT / 8, 256, 0, stream>>>(entF, qsub, relhF, qrel, oc_k, oc_kb, Ybuf);
  conv_gemm<<<dim3(NT / 32, KSP), 256, 0, stream>>>(Ybuf, fwTo, Zp);
  conv_finalize<<<NT * H / 256, 256, 0, stream>>>(Zp, oc_fb, Zo);

  conv_relu<<<NT / 8, 256, 0, stream>>>(entF, qsub, entF, qobj, rc_k, rc_kb, Ybuf);
  conv_gemm<<<dim3(NT / 32, KSP), 256, 0, stream>>>(Ybuf, fwTr, Zp);
  conv_finalize<<<NT * H / 256, 256, 0, stream>>>(Zp, rc_fb, Zr);

  // logits: ent-logits with XCD swizzle (157 m-tiles -> padded to 160),
  // rel-logits plain (1 m-tile).
  int nmt = MPE / 256;                       // 157
  int grid_swz = ((nmt + 7) / 8) * 8 * 16;   // 2560
  logits_gemm3<<<grid_swz, 256, 0, stream>>>(Zo, FTe, out, NE, MPE, nmt, 1);
  logits_gemm3<<<dim3(NT / 64, NR / 256), 256, 0, stream>>>(Zr, FTr, out + (size_t)NT * NE, NR, NR, 1, 0);
}

// Round 9
// 2320.734 us; speedup vs baseline: 2.0602x; 2.0602x over previous
//
#include <hip/hip_runtime.h>
#include <cmath>

// ---------------------------------------------------------------------------
// Tconv_35450660061268 — R12.
//   * R11 post-mortem: lb(256,8) capped VGPRs at 64 -> acc[8][8] spilled to
//     scratch (VGPR 32, FETCH 3.8GB, WRITE 8GB, 2.5ms). Fix: keep the
//     17.4KB LDS tile (sZ[64][68], two K chunks) but lb(256,4) -> VGPR cap
//     128, no spill; occupancy ~5-6 blocks/CU (vs R10's 4, LDS-limited).
//   * everything else unchanged from R10/R11 (XCD swizzle kept).
// ---------------------------------------------------------------------------

namespace {

constexpr int H   = 128;
constexpr int KK  = 4;
constexpr int C   = 32;
constexpr int NE  = 40000;
constexpr int NR  = 256;
constexpr int T   = 4;
constexpr int E   = 100000;
constexpr int NT  = 1024;
constexpr int PIN = 388;     // H*KK - H + KK
constexpr int MW  = 1280;    // mask words per relation (padded; 1250 used)
constexpr int MWU = 1250;
constexpr int KC  = 4096;    // conv GEMM K (C*H)
constexpr int KSP = 32;      // conv split-K slices (K-slice = 128)
constexpr int MPE = 40192;   // NE padded to 256 (157*256)
constexpr size_t NEH = (size_t)NE * H;

__device__ __forceinline__ float sigm(float x) { return 1.0f / (1.0f + expf(-x)); }

// ---- row L2-normalize, one wave per row (init only) ------------------------
__global__ __launch_bounds__(256) void norm_rows(const float* __restrict__ in,
                                                 float* __restrict__ out, int n) {
  int row  = blockIdx.x * 4 + (threadIdx.x >> 6);
  int lane = threadIdx.x & 63;
  if (row >= n) return;
  const float2* ip = reinterpret_cast<const float2*>(in + (size_t)row * H);
  float2 v = ip[lane];
  float ss = v.x * v.x + v.y * v.y;
#pragma unroll
  for (int off = 32; off; off >>= 1) ss += __shfl_xor(ss, off);
  float inv = 1.0f / fmaxf(sqrtf(ss), 1e-12f);
  float2 o; o.x = v.x * inv; o.y = v.y * inv;
  reinterpret_cast<float2*>(out + (size_t)row * H)[lane] = o;
}

__global__ void copy_vec(const float* __restrict__ a, float* __restrict__ b, int n) {
  int i = blockIdx.x * blockDim.x + threadIdx.x;
  if (i < n) b[i] = a[i];
}

__global__ __launch_bounds__(256) void transpose128(const float* __restrict__ in,
                                                    float* __restrict__ out) {
  int i = blockIdx.x * 256 + threadIdx.x;   // grid 64
  int o = i >> 7, k = i & 127;
  out[k * H + o] = in[o * H + k];
}

// fwT[k*128 + o] = fw[o*4096 + k]   (128 x 4096 -> 4096 x 128), grid 2048
__global__ __launch_bounds__(256) void transposeFW(const float* __restrict__ in,
                                                   float* __restrict__ out) {
  int i = blockIdx.x * 256 + threadIdx.x;
  int o = i >> 12, k = i & 4095;
  out[(size_t)k * 128 + o] = in[i];
}

// tiled transpose: in[R][128] -> out[128][MP], grid MP/64 blocks.
// rows r >= R zero-filled.
__global__ __launch_bounds__(256) void transposeF(const float* __restrict__ in,
                                                  float* __restrict__ out,
                                                  int R, int MP) {
  __shared__ float tile[64][129];
  int r0 = blockIdx.x * 64;
  int t = threadIdx.x;
  for (int idx = t; idx < 64 * 128; idx += 256) {
    int q = idx >> 7, k = idx & 127;
    int r = r0 + q;
    tile[q][k] = (r < R) ? in[(size_t)r * H + k] : 0.0f;
  }
  __syncthreads();
  for (int idx = t; idx < 64 * 128; idx += 256) {
    int k = idx >> 6, q = idx & 63;
    out[(size_t)k * MP + r0 + q] = tile[q][k];
  }
}

// ---- mmt GRU pair + gated update + v = mmt_new @ tc_w^T + tc_b (1 block) ---
__global__ __launch_bounds__(128) void mmt_step(
    const float* __restrict__ mmt_in,
    const float* __restrict__ w1, const float* __restrict__ bi1, const float* __restrict__ bh1,
    const float* __restrict__ w2, const float* __restrict__ bi2, const float* __restrict__ bh2,
    const float* __restrict__ tcw, const float* __restrict__ tcb,
    float* __restrict__ mmt_out, float* __restrict__ vout) {
  __shared__ float sm[H], sm2[H];
  int t = threadIdx.x;
  sm[t] = mmt_in[t];
  __syncthreads();
  float g1r = bi1[t], g1z = bi1[H + t], g1n = bi1[2 * H + t];
  float g2r = bi2[t], g2z = bi2[H + t], g2n = bi2[2 * H + t];
  {
    const float4* r1p = reinterpret_cast<const float4*>(w1 + (size_t)t * H);
    const float4* z1p = reinterpret_cast<const float4*>(w1 + (size_t)(H + t) * H);
    const float4* n1p = reinterpret_cast<const float4*>(w1 + (size_t)(2 * H + t) * H);
    const float4* r2p = reinterpret_cast<const float4*>(w2 + (size_t)t * H);
    const float4* z2p = reinterpret_cast<const float4*>(w2 + (size_t)(H + t) * H);
    const float4* n2p = reinterpret_cast<const float4*>(w2 + (size_t)(2 * H + t) * H);
    const float4* x4 = reinterpret_cast<const float4*>(sm);
    for (int k = 0; k < 32; k++) {
      float4 x = x4[k];
      float4 a = r1p[k], b = z1p[k], c = n1p[k], d = r2p[k], e = z2p[k], f = n2p[k];
      g1r += x.x * a.x + x.y * a.y + x.z * a.z + x.w * a.w;
      g1z += x.x * b.x + x.y * b.y + x.z * b.z + x.w * b.w;
      g1n += x.x * c.x + x.y * c.y + x.z * c.z + x.w * c.w;
      g2r += x.x * d.x + x.y * d.y + x.z * d.z + x.w * d.w;
      g2z += x.x * e.x + x.y * e.y + x.z * e.z + x.w * e.w;
      g2n += x.x * f.x + x.y * f.y + x.z * f.z + x.w * f.w;
    }
  }
  float r1 = sigm(g1r + bh1[t]), z1 = sigm(g1z + bh1[H + t]);
  float n1 = tanhf(g1n + r1 * bh1[2 * H + t]);
  float nmmt = (1.0f - z1) * n1;
  float r2 = sigm(g2r + bh2[t]), z2 = sigm(g2z + bh2[H + t]);
  float n2 = tanhf(g2n + r2 * bh2[2 * H + t]);
  float gg = (1.0f - z2) * n2;
  float m  = sm[t];
  float mo = m + gg * (nmmt - m);
  mmt_out[t] = mo;
  sm2[t] = mo;
  __syncthreads();
  float v = tcb[t];
  {
    const float4* wp = reinterpret_cast<const float4*>(tcw + (size_t)t * H);
    const float4* x4 = reinterpret_cast<const float4*>(sm2);
    for (int k = 0; k < 32; k++) {
      float4 x = x4[k], w = wp[k];
      v += x.x * w.x + x.y * w.y + x.z * w.z + x.w * w.w;
    }
  }
  vout[t] = v;
}

// ---- build MT[p*H+o] = M[o][p] (k-major tconv map) -------------------------
__global__ __launch_bounds__(128) void build_M(const float* __restrict__ v,
                                               const float* __restrict__ pw,
                                               float* __restrict__ MT) {
  int o = blockIdx.x, p = threadIdx.x;
  __shared__ float sp[PIN];
  __shared__ float sv[H];
  for (int i = p; i < PIN; i += H) sp[i] = pw[(size_t)o * PIN + i];
  sv[p] = v[p];
  __syncthreads();
  float acc = 0.0f;
  int jlo = p - 31 > 0 ? p - 31 : 0;
  int jhi = p < 96 ? p : 96;
#pragma unroll
  for (int k = 0; k < KK; k++)
    for (int j = jlo; j <= jhi; j++) acc += sp[k * 97 + j] * sv[k * 32 + (p - j)];
  MT[p * H + o] = acc;
}

// ===========================================================================
// Register-tiled GEMM family (unchanged core from R2).
// ===========================================================================
__global__ __launch_bounds__(256) void gemm_bias(const float* __restrict__ X,
                                                 const float* __restrict__ WT,
                                                 const float* __restrict__ bias,
                                                 float* __restrict__ out) {
  __shared__ float sX[64 * H];
  int t = threadIdx.x;
  int base = blockIdx.x * 64;
  const float4* gx = reinterpret_cast<const float4*>(X + (size_t)base * H);
  float4* sx4 = reinterpret_cast<float4*>(sX);
#pragma unroll
  for (int i = 0; i < 8; i++) sx4[t + 256 * i] = gx[t + 256 * i];
  __syncthreads();
  int oq = (t & 31) * 4, ng = (t >> 5) * 8;
  float acc[8][4] = {};
  for (int k = 0; k < H; k += 4) {
    float4 w0 = *reinterpret_cast<const float4*>(&WT[(k + 0) * H + oq]);
    float4 w1 = *reinterpret_cast<const float4*>(&WT[(k + 1) * H + oq]);
    float4 w2 = *reinterpret_cast<const float4*>(&WT[(k + 2) * H + oq]);
    float4 w3 = *reinterpret_cast<const float4*>(&WT[(k + 3) * H + oq]);
#pragma unroll
    for (int m = 0; m < 8; m++) {
      float4 x = *reinterpret_cast<const float4*>(&sX[(ng + m) * H + k]);
      acc[m][0] += x.x * w0.x + x.y * w1.x + x.z * w2.x + x.w * w3.x;
      acc[m][1] += x.x * w0.y + x.y * w1.y + x.z * w2.y + x.w * w3.y;
      acc[m][2] += x.x * w0.z + x.y * w1.z + x.z * w2.z + x.w * w3.z;
      acc[m][3] += x.x * w0.w + x.y * w1.w + x.z * w2.w + x.w * w3.w;
    }
  }
  float4 b4 = *reinterpret_cast<const float4*>(&bias[oq]);
#pragma unroll
  for (int m = 0; m < 8; m++) {
    float4 o4 = {acc[m][0] + b4.x, acc[m][1] + b4.y, acc[m][2] + b4.z, acc[m][3] + b4.w};
    *reinterpret_cast<float4*>(&out[(size_t)(base + ng + m) * H + oq]) = o4;
  }
}

// RGCN layer fused: out = relu((A@wn)*inv_deg + Hm@ws + b); optional row-norm.
__global__ __launch_bounds__(256) void gemm_rgcn(const float* __restrict__ A,
                                                 const float* __restrict__ Hm,
                                                 const float* __restrict__ wn,
                                                 const float* __restrict__ ws,
                                                 const float* __restrict__ bias,
                                                 const int* __restrict__ deg,
                                                 float* __restrict__ out,
                                                 int donorm) {
  __shared__ float sA[32 * H];
  __shared__ float sH[32 * H];
  int t = threadIdx.x;
  int base = blockIdx.x * 32;
  const float4* ga = reinterpret_cast<const float4*>(A + (size_t)base * H);
  const float4* gh = reinterpret_cast<const float4*>(Hm + (size_t)base * H);
  float4* sa4 = reinterpret_cast<float4*>(sA);
  float4* sh4 = reinterpret_cast<float4*>(sH);
#pragma unroll
  for (int i = 0; i < 4; i++) { sa4[t + 256 * i] = ga[t + 256 * i]; sh4[t + 256 * i] = gh[t + 256 * i]; }
  __syncthreads();
  int oq = (t & 31) * 4, ng = (t >> 5) * 4;
  float accA[4][4] = {}, accS[4][4] = {};
  for (int k = 0; k < H; k += 4) {
    float4 n0 = *reinterpret_cast<const float4*>(&wn[(k + 0) * H + oq]);
    float4 n1 = *reinterpret_cast<const float4*>(&wn[(k + 1) * H + oq]);
    float4 n2 = *reinterpret_cast<const float4*>(&wn[(k + 2) * H + oq]);
    float4 n3 = *reinterpret_cast<const float4*>(&wn[(k + 3) * H + oq]);
    float4 s0 = *reinterpret_cast<const float4*>(&ws[(k + 0) * H + oq]);
    float4 s1 = *reinterpret_cast<const float4*>(&ws[(k + 1) * H + oq]);
    float4 s2 = *reinterpret_cast<const float4*>(&ws[(k + 2) * H + oq]);
    float4 s3 = *reinterpret_cast<const float4*>(&ws[(k + 3) * H + oq]);
#pragma unroll
    for (int m = 0; m < 4; m++) {
      float4 a = *reinterpret_cast<const float4*>(&sA[(ng + m) * H + k]);
      float4 h = *reinterpret_cast<const float4*>(&sH[(ng + m) * H + k]);
      accA[m][0] += a.x * n0.x + a.y * n1.x + a.z * n2.x + a.w * n3.x;
      accA[m][1] += a.x * n0.y + a.y * n1.y + a.z * n2.y + a.w * n3.y;
      accA[m][2] += a.x * n0.z + a.y * n1.z + a.z * n2.z + a.w * n3.z;
      accA[m][3] += a.x * n0.w + a.y * n1.w + a.z * n2.w + a.w * n3.w;
      accS[m][0] += h.x * s0.x + h.y * s1.x + h.z * s2.x + h.w * s3.x;
      accS[m][1] += h.x * s0.y + h.y * s1.y + h.z * s2.y + h.w * s3.y;
      accS[m][2] += h.x * s0.z + h.y * s1.z + h.z * s2.z + h.w * s3.z;
      accS[m][3] += h.x * s0.w + h.y * s1.w + h.z * s2.w + h.w * s3.w;
    }
  }
  float4 b4 = *reinterpret_cast<const float4*>(&bias[oq]);
  float v[4][4];
#pragma unroll
  for (int m = 0; m < 4; m++) {
    float inv = 1.0f / fmaxf((float)deg[base + ng + m], 1.0f);
    v[m][0] = fmaxf(accA[m][0] * inv + accS[m][0] + b4.x, 0.0f);
    v[m][1] = fmaxf(accA[m][1] * inv + accS[m][1] + b4.y, 0.0f);
    v[m][2] = fmaxf(accA[m][2] * inv + accS[m][2] + b4.z, 0.0f);
    v[m][3] = fmaxf(accA[m][3] * inv + accS[m][3] + b4.w, 0.0f);
  }
  if (donorm) {
#pragma unroll
    for (int m = 0; m < 4; m++) {
      float ss = v[m][0]*v[m][0] + v[m][1]*v[m][1] + v[m][2]*v[m][2] + v[m][3]*v[m][3];
#pragma unroll
      for (int off = 16; off; off >>= 1) ss += __shfl_xor(ss, off);
      float inv = 1.0f / fmaxf(sqrtf(ss), 1e-12f);
      v[m][0] *= inv; v[m][1] *= inv; v[m][2] *= inv; v[m][3] *= inv;
    }
  }
#pragma unroll
  for (int m = 0; m < 4; m++) {
    float4 o4 = {v[m][0], v[m][1], v[m][2], v[m][3]};
    *reinterpret_cast<float4*>(&out[(size_t)(base + ng + m) * H + oq]) = o4;
  }
}

// out = e + sigm(e@WT+b)*(nf - e)
__global__ __launch_bounds__(256) void gemm_update(const float* __restrict__ Xe,
                                                   const float* __restrict__ WT,
                                                   const float* __restrict__ bias,
                                                   const float* __restrict__ nf,
                                                   float* __restrict__ out) {
  __shared__ float sX[64 * H];
  int t = threadIdx.x;
  int base = blockIdx.x * 64;
  const float4* gx = reinterpret_cast<const float4*>(Xe + (size_t)base * H);
  float4* sx4 = reinterpret_cast<float4*>(sX);
#pragma unroll
  for (int i = 0; i < 8; i++) sx4[t + 256 * i] = gx[t + 256 * i];
  __syncthreads();
  int oq = (t & 31) * 4, ng = (t >> 5) * 8;
  float acc[8][4] = {};
  for (int k = 0; k < H; k += 4) {
    float4 w0 = *reinterpret_cast<const float4*>(&WT[(k + 0) * H + oq]);
    float4 w1 = *reinterpret_cast<const float4*>(&WT[(k + 1) * H + oq]);
    float4 w2 = *reinterpret_cast<const float4*>(&WT[(k + 2) * H + oq]);
    float4 w3 = *reinterpret_cast<const float4*>(&WT[(k + 3) * H + oq]);
#pragma unroll
    for (int m = 0; m < 8; m++) {
      float4 x = *reinterpret_cast<const float4*>(&sX[(ng + m) * H + k]);
      acc[m][0] += x.x * w0.x + x.y * w1.x + x.z * w2.x + x.w * w3.x;
      acc[m][1] += x.x * w0.y + x.y * w1.y + x.z * w2.y + x.w * w3.y;
      acc[m][2] += x.x * w0.z + x.y * w1.z + x.z * w2.z + x.w * w3.z;
      acc[m][3] += x.x * w0.w + x.y * w1.w + x.z * w2.w + x.w * w3.w;
    }
  }
  float4 b4 = *reinterpret_cast<const float4*>(&bias[oq]);
#pragma unroll
  for (int m = 0; m < 8; m++) {
    size_t row = (size_t)(base + ng + m) * H;
    float4 e4 = *reinterpret_cast<const float4*>(&sX[(ng + m) * H + oq]);
    float4 f4 = *reinterpret_cast<const float4*>(&nf[row + oq]);
    float4 o4 = {e4.x + sigm(acc[m][0] + b4.x) * (f4.x - e4.x),
                 e4.y + sigm(acc[m][1] + b4.y) * (f4.y - e4.y),
                 e4.z + sigm(acc[m][2] + b4.z) * (f4.z - e4.z),
                 e4.w + sigm(acc[m][3] + b4.w) * (f4.w - e4.w)};
    *reinterpret_cast<float4*>(&out[row + oq]) = o4;
  }
}

// ===========================================================================
// Edge prep: rel-bitmask scatter + dst-degree histogram in one pass over E.
// ===========================================================================
__global__ __launch_bounds__(256) void edge_prep(const int* __restrict__ s,
                                                 const int* __restrict__ d,
                                                 const int* __restrict__ r,
                                                 unsigned int* __restrict__ mask,
                                                 int* __restrict__ deg) {
  int e = blockIdx.x * 256 + threadIdx.x;
  if (e >= E) return;
  int ri = r[e], si = s[e], di = d[e];
  atomicOr(&mask[(size_t)ri * MW + (si >> 5)], 1u << (si & 31));
  atomicOr(&mask[(size_t)ri * MW + (di >> 5)], 1u << (di & 31));
  atomicAdd(&deg[di], 1);
}

// wave-shfl scan over deg -> rowptr (exclusive) + wpos copy
__global__ __launch_bounds__(1024) void scan_deg(const int* __restrict__ deg,
                                                 int* __restrict__ rowptr,
                                                 int* __restrict__ wpos) {
  __shared__ int wsum[16];
  __shared__ int carry_s;
  int tid = threadIdx.x, lane = tid & 63, w = tid >> 6;
  if (tid == 0) carry_s = 0;
  __syncthreads();
  for (int base = 0; base < NE; base += 1024) {
    int idx = base + tid;
    int v = idx < NE ? deg[idx] : 0;
    int x = v;
#pragma unroll
    for (int off = 1; off < 64; off <<= 1) {
      int y = __shfl_up(x, off, 64);
      if (lane >= off) x += y;
    }
    if (lane == 63) wsum[w] = x;
    __syncthreads();
    int carry = carry_s;
    int wpre = 0;
    for (int i = 0; i < w; i++) wpre += wsum[i];
    int excl = carry + wpre + x - v;
    if (idx < NE) { rowptr[idx] = excl; wpos[idx] = excl; }
    __syncthreads();
    if (tid == 1023) carry_s = carry + wpre + x;
  }
  __syncthreads();
  if (tid == 0) rowptr[NE] = carry_s;
}

__global__ __launch_bounds__(256) void edge_fill(const int* __restrict__ d,
                                                 int* __restrict__ wpos,
                                                 int* __restrict__ elist) {
  int e = blockIdx.x * 256 + threadIdx.x;
  if (e >= E) return;
  int p = atomicAdd(&wpos[d[e]], 1);
  elist[p] = e;
}

// agg[n][dim] = sum_{e: d[e]==n} h[s[e]][dim] + ef[r[e]][dim]   (2 nodes/blk)
__global__ __launch_bounds__(256) void rgcn_gather(const float* __restrict__ h,
                                                   const float* __restrict__ ef,
                                                   const int* __restrict__ rowptr,
                                                   const int* __restrict__ elist,
                                                   const int* __restrict__ s,
                                                   const int* __restrict__ r,
                                                   float* __restrict__ agg) {
  int node = blockIdx.x * 2 + (threadIdx.x >> 7);
  int dim  = threadIdx.x & 127;
  int b = rowptr[node], e2 = rowptr[node + 1];
  float acc = 0.0f;
  for (int i = b; i < e2; i++) {
    int e = elist[i];
    acc += h[(size_t)s[e] * H + dim] + ef[(size_t)r[e] * H + dim];
  }
  agg[(size_t)node * H + dim] = acc;
}

// ---- _agg_rel masked sum: 32 partitions per relation -----------------------
__global__ __launch_bounds__(128) void agg_rel_sum(const unsigned int* __restrict__ mask,
                                                   const float* __restrict__ ent,
                                                   float* __restrict__ rsum,
                                                   float* __restrict__ rcnt) {
  int rel = blockIdx.x, part = blockIdx.y, tid = threadIdx.x;
  const int WPS = (MWU + 31) / 32;  // 40
  int w0 = part * WPS;
  int w1 = w0 + WPS < MWU ? w0 + WPS : MWU;
  float acc = 0.0f, cnt = 0.0f;
  const unsigned int* mrow = mask + (size_t)rel * MW;
  for (int w = w0; w < w1; w++) {
    unsigned int bits = mrow[w];
    if (!bits) continue;
    cnt += (float)__popc(bits);
    int base = w << 5;
    while (bits) {
      int b = __ffs(bits) - 1;
      bits &= bits - 1;
      acc += ent[(size_t)(base + b) * H + tid];
    }
  }
  if (acc != 0.0f) atomicAdd(&rsum[rel * H + tid], acc);
  if (tid == 0 && cnt != 0.0f) atomicAdd(&rcnt[rel], cnt);
}

// ---- relation GRU (finalize fused) + row normalize -------------------------
__global__ __launch_bounds__(128) void rel_gru(const float* __restrict__ rsum,
                                               const float* __restrict__ rcnt,
                                               const float* __restrict__ rel_param,
                                               const float* __restrict__ relh,
                                               const float* __restrict__ wih,
                                               const float* __restrict__ whh,
                                               const float* __restrict__ bih,
                                               const float* __restrict__ bhh,
                                               float* __restrict__ outp) {
  int rel = blockIdx.x, tid = threadIdx.x;
  __shared__ float sx[2 * H], sh[H], red[H];
  float c = rcnt[rel];
  sx[tid]     = c > 0.0f ? rsum[rel * H + tid] / fmaxf(c, 1.0f) : 0.0f;
  sx[H + tid] = rel_param[rel * H + tid];
  sh[tid]     = relh[rel * H + tid];
  __syncthreads();
  float gr = bih[tid], gz = bih[H + tid], gn = bih[2 * H + tid];
  {
    const float4* rp = reinterpret_cast<const float4*>(wih + (size_t)tid * 2 * H);
    const float4* zp = reinterpret_cast<const float4*>(wih + (size_t)(H + tid) * 2 * H);
    const float4* np = reinterpret_cast<const float4*>(wih + (size_t)(2 * H + tid) * 2 * H);
    const float4* x4 = reinterpret_cast<const float4*>(sx);
    for (int k = 0; k < 64; k++) {
      float4 x = x4[k];
      float4 a = rp[k], b = zp[k], cc = np[k];
      gr += x.x * a.x + x.y * a.y + x.z * a.z + x.w * a.w;
      gz += x.x * b.x + x.y * b.y + x.z * b.z + x.w * b.w;
      gn += x.x * cc.x + x.y * cc.y + x.z * cc.z + x.w * cc.w;
    }
  }
  float hr = bhh[tid], hz = bhh[H + tid], hn = bhh[2 * H + tid];
  {
    const float4* rp = reinterpret_cast<const float4*>(whh + (size_t)tid * H);
    const float4* zp = reinterpret_cast<const float4*>(whh + (size_t)(H + tid) * H);
    const float4* np = reinterpret_cast<const float4*>(whh + (size_t)(2 * H + tid) * H);
    const float4* h4 = reinterpret_cast<const float4*>(sh);
    for (int k = 0; k < 32; k++) {
      float4 x = h4[k];
      float4 a = rp[k], b = zp[k], cc = np[k];
      hr += x.x * a.x + x.y * a.y + x.z * a.z + x.w * a.w;
      hz += x.x * b.x + x.y * b.y + x.z * b.z + x.w * b.w;
      hn += x.x * cc.x + x.y * cc.y + x.z * cc.z + x.w * cc.w;
    }
  }
  float r = sigm(gr + hr), z = sigm(gz + hz), nn = tanhf(gn + r * hn);
  float val = (1.0f - z) * nn + z * sh[tid];
  red[tid] = val * val;
  __syncthreads();
  for (int s2 = 64; s2 > 0; s2 >>= 1) {
    if (tid < s2) red[tid] += red[tid + s2];
    __syncthreads();
  }
  float inv = 1.0f / fmaxf(sqrtf(red[0]), 1e-12f);
  outp[rel * H + tid] = val * inv;
}

// ===========================================================================
// ConvTransE front — stage A: materialize Y[NT][4096] = relu(conv(x)).
// ===========================================================================
__global__ __launch_bounds__(256) void conv_relu(const float* __restrict__ fa,
                                                 const int* __restrict__ ia,
                                                 const float* __restrict__ fbm,
                                                 const int* __restrict__ ib,
                                                 const float* __restrict__ ck,
                                                 const float* __restrict__ ckb,
                                                 float* __restrict__ Y) {
  __shared__ float sx[8 * 2 * H];   // 8 KB
  __shared__ float sck[C * 6];
  __shared__ float sckb[C];
  int tid = threadIdx.x, q0 = blockIdx.x * 8;
  if (tid < C * 6) sck[tid] = ck[tid];
  if (tid < C)     sckb[tid] = ckb[tid];
#pragma unroll
  for (int i = tid; i < 2048; i += 256) {
    int q = i >> 8, half = (i >> 7) & 1, p = i & 127;
    int node = (half ? ib : ia)[q0 + q];
    sx[i] = (half ? fbm : fa)[(size_t)node * H + p];
  }
  __syncthreads();
  for (int i4 = tid; i4 < 8192; i4 += 256) {
    int q = i4 >> 10, rr = i4 & 1023;
    int c = rr >> 5, p0 = (rr & 31) << 2;
    const float* x0 = &sx[q * 256];
    const float* x1 = x0 + 128;
    float k00 = sck[c * 6 + 0], k01 = sck[c * 6 + 1], k02 = sck[c * 6 + 2];
    float k10 = sck[c * 6 + 3], k11 = sck[c * 6 + 4], k12 = sck[c * 6 + 5];
    float bb = sckb[c];
    float4 o;
    float* op = &o.x;
#pragma unroll
    for (int dd = 0; dd < 4; dd++) {
      int p = p0 + dd;
      float acc = bb + x0[p] * k01 + x1[p] * k11;
      if (p - 1 >= 0)  acc += x0[p - 1] * k00 + x1[p - 1] * k10;
      if (p + 1 < H)   acc += x0[p + 1] * k02 + x1[p + 1] * k12;
      op[dd] = fmaxf(acc, 0.0f);
    }
    *reinterpret_cast<float4*>(&Y[(size_t)(q0 + q) * KC + rr * 4]) = o;
  }
}

// ===========================================================================
// ConvTransE front — stage B: split-K GEMM, Zp[ks] = Y[:,ksl] @ fwT[ksl,:].
// ===========================================================================
__global__ __launch_bounds__(256) void conv_gemm(const float* __restrict__ Y,
                                                 const float* __restrict__ fwT,
                                                 float* __restrict__ Zp) {
  int t = threadIdx.x;
  int mb = blockIdx.x * 32, ks = blockIdx.y;
  int oq = (t & 31) * 4, ng = (t >> 5) * 4;
  const float* yb = Y + (size_t)(mb + ng) * KC + ks * 128;
  const float* wb = fwT + (size_t)ks * 128 * H + oq;
  float acc[4][4] = {};
  for (int k = 0; k < 128; k += 4) {
    float4 w0 = *reinterpret_cast<const float4*>(wb + (size_t)(k + 0) * H);
    float4 w1 = *reinterpret_cast<const float4*>(wb + (size_t)(k + 1) * H);
    float4 w2 = *reinterpret_cast<const float4*>(wb + (size_t)(k + 2) * H);
    float4 w3 = *reinterpret_cast<const float4*>(wb + (size_t)(k + 3) * H);
#pragma unroll
    for (int m = 0; m < 4; m++) {
      float4 y = *reinterpret_cast<const float4*>(yb + (size_t)m * KC + k);
      acc[m][0] += y.x * w0.x + y.y * w1.x + y.z * w2.x + y.w * w3.x;
      acc[m][1] += y.x * w0.y + y.y * w1.y + y.z * w2.y + y.w * w3.y;
      acc[m][2] += y.x * w0.z + y.y * w1.z + y.z * w2.z + y.w * w3.z;
      acc[m][3] += y.x * w0.w + y.y * w1.w + y.z * w2.w + y.w * w3.w;
    }
  }
  float* zb = Zp + (size_t)ks * NT * H;
#pragma unroll
  for (int m = 0; m < 4; m++) {
    float4 o4 = {acc[m][0], acc[m][1], acc[m][2], acc[m][3]};
    *reinterpret_cast<float4*>(&zb[(size_t)(mb + ng + m) * H + oq]) = o4;
  }
}

__global__ __launch_bounds__(256) void conv_finalize(const float* __restrict__ Zp,
                                                     const float* __restrict__ fb,
                                                     float* __restrict__ Z) {
  int i = blockIdx.x * 256 + threadIdx.x;  // NT*H / 256
  int o = i & 127;
  float v = fb[o];
#pragma unroll
  for (int s = 0; s < KSP; s++) v += Zp[(size_t)s * NT * H + i];
  Z[i] = fmaxf(v, 0.0f);
}

// ===========================================================================
// logits GEMM v4: out[q][m] = sum_k Z[q][k] * FT[k][m].
// XCD swizzle (FT L2-resident) + K staged in two 64-row LDS chunks (17.4KB).
// lb(256,4): VGPR cap 128 so acc[8][8] stays in registers (R11's lb(256,8)
// spilled it to scratch: 12GB traffic, 17x slower).
// ===========================================================================
__global__ __launch_bounds__(256, 4) void logits_gemm3(const float* __restrict__ Z,
                                                       const float* __restrict__ FT,
                                                       float* __restrict__ out,
                                                       int M, int MP, int nmt, int swiz) {
  __shared__ float sZ[64][68];
  int t = threadIdx.x;
  int bq, bm;
  if (swiz) {
    int id = blockIdx.x;
    int xcd = id & 7, w = id >> 3;
    int mt = (w >> 4) * 8 + xcd, j = w & 15;
    if (mt >= nmt) return;
    bq = j * 64; bm = mt * 256;
  } else {
    bq = blockIdx.x * 64; bm = blockIdx.y * 256;
  }
  int tx = t & 31, ty = t >> 5;
  int m0 = bm + tx * 8, q0 = ty * 8;
  const float* ftp = FT + m0;
  float acc[8][8] = {};
  for (int kc = 0; kc < H; kc += 64) {
    __syncthreads();
    for (int idx = t; idx < 64 * 64; idx += 256) {
      int q = idx >> 6, k = idx & 63;
      sZ[k][q] = Z[(size_t)(bq + q) * H + kc + k];
    }
    __syncthreads();
#pragma unroll 2
    for (int k = 0; k < 64; k++) {
      float4 fa = *reinterpret_cast<const float4*>(ftp + (size_t)(kc + k) * MP);
      float4 fb = *reinterpret_cast<const float4*>(ftp + (size_t)(kc + k) * MP + 4);
      float4 za = *reinterpret_cast<const float4*>(&sZ[k][q0]);
      float4 zb = *reinterpret_cast<const float4*>(&sZ[k][q0 + 4]);
      float zq[8] = {za.x, za.y, za.z, za.w, zb.x, zb.y, zb.z, zb.w};
      float fm[8] = {fa.x, fa.y, fa.z, fa.w, fb.x, fb.y, fb.z, fb.w};
#pragma unroll
      for (int i = 0; i < 8; i++)
#pragma unroll
        for (int j = 0; j < 8; j++) acc[i][j] += zq[i] * fm[j];
    }
  }
  if (m0 >= M) return;
#pragma unroll
  for (int i = 0; i < 8; i++) {
    size_t row = (size_t)(bq + q0 + i) * (size_t)M + m0;
    float4 o1 = {acc[i][0], acc[i][1], acc[i][2], acc[i][3]};
    float4 o2 = {acc[i][4], acc[i][5], acc[i][6], acc[i][7]};
    *reinterpret_cast<float4*>(&out[row]) = o1;
    *reinterpret_cast<float4*>(&out[row + 4]) = o2;
  }
}

}  // namespace

extern "C" void kernel_launch(void* const* d_in, const int* in_sizes, int n_in,
                              void* d_out, int out_size, void* d_ws, size_t ws_size,
                              hipStream_t stream) {
  (void)in_sizes; (void)n_in; (void)out_size; (void)ws_size;
  const float* ent_embeds = (const float*)d_in[0];
  const float* rel_embeds = (const float*)d_in[1];
  const float* mmt_embed  = (const float*)d_in[2];
  const float* tc_w  = (const float*)d_in[3];
  const float* tc_b  = (const float*)d_in[4];
  const float* tc_pw = (const float*)d_in[5];
  const float* tc_pb = (const float*)d_in[6];
  const float* g1_wih = (const float*)d_in[7];
  const float* g1_whh = (const float*)d_in[8];
  const float* g1_bih = (const float*)d_in[9];
  const float* g1_bhh = (const float*)d_in[10];
  const float* l1_wih = (const float*)d_in[11];
  const float* l1_bih = (const float*)d_in[13];
  const float* l1_bhh = (const float*)d_in[14];
  const float* l2_wih = (const float*)d_in[15];
  const float* l2_bih = (const float*)d_in[17];
  const float* l2_bhh = (const float*)d_in[18];
  const float* lin_w = (const float*)d_in[19];
  const float* lin_b = (const float*)d_in[20];
  const float* rgcn_wn = (const float*)d_in[21];
  const float* rgcn_ws = (const float*)d_in[22];
  const float* rgcn_b  = (const float*)d_in[23];
  const float* oc_k  = (const float*)d_in[24];
  const float* oc_kb = (const float*)d_in[25];
  const float* oc_fw = (const float*)d_in[26];
  const float* oc_fb = (const float*)d_in[27];
  const float* rc_k  = (const float*)d_in[28];
  const float* rc_kb = (const float*)d_in[29];
  const float* rc_fw = (const float*)d_in[30];
  const float* rc_fb = (const float*)d_in[31];
  const int* src  = (const int*)d_in[32];
  const int* dst  = (const int*)d_in[33];
  const int* rid  = (const int*)d_in[34];
  const int* qsub = (const int*)d_in[35];
  const int* qrel = (const int*)d_in[36];
  const int* qobj = (const int*)d_in[37];

  float* out = (float*)d_out;
  float* ws  = (float*)d_ws;

  // ---- d_ws layout (floats) ----
  size_t off = 0;
  float* relhB[3] = {ws + off, ws + off + (size_t)NR * H, ws + off + 2 * (size_t)NR * H};
  off += 3 * (size_t)NR * H;
  float* rel_sum = ws + off; off += (size_t)NR * H;
  float* rcnt    = ws + off; off += NR;
  float* mmtbuf0 = ws + off; off += H;
  float* mmtbuf1 = ws + off; off += H;
  float* vbuf    = ws + off; off += H;
  float* MT      = ws + off; off += (size_t)H * H;
  float* WTlin   = ws + off; off += (size_t)H * H;
  float* Zo      = ws + off; off += (size_t)NT * H;
  float* Zr      = ws + off; off += (size_t)NT * H;
  float* FTe     = ws + off; off += (size_t)H * MPE;    // 5.14M floats
  float* FTr     = ws + off; off += (size_t)H * NR;
  unsigned int* mask = (unsigned int*)(ws + off); off += (size_t)NR * MW;

  // ---- d_out as scratch: 4 rotating NE*H buffers + CSR ints in the tail ----
  float* B[4] = {out, out + NEH, out + 2 * NEH, out + 3 * NEH};
  int* itail   = (int*)(out + 4 * NEH);
  int* deg     = itail;
  int* rowptr  = itail + NE;
  int* wpos    = itail + 2 * NE + 1;
  int* elist   = itail + 3 * NE + 1;
  float* mmtb[2] = {mmtbuf0, mmtbuf1};
  // conv scratch (dead before logits write out). All below 10.24M floats;
  // final entities end up in B[2] = [10.24M, 15.36M) — no overlap.
  float* Ybuf  = out;                                     // [0, 4.19M)
  float* Zp    = out + (size_t)NT * KC;                   // [4.19M, 8.39M)
  float* fwTo  = Zp + (size_t)KSP * NT * H;               // [8.39M, 8.91M)
  float* fwTr  = fwTo + (size_t)KC * H;                   // [8.91M, 9.44M)

  norm_rows<<<(NE + 3) / 4, 256, 0, stream>>>(ent_embeds, B[0], NE);
  norm_rows<<<(NR + 3) / 4, 256, 0, stream>>>(rel_embeds, relhB[0], NR);
  copy_vec<<<1, 128, 0, stream>>>(mmt_embed, mmtbuf0, H);
  transpose128<<<64, 256, 0, stream>>>(lin_w, WTlin);

  int cur = 0, curRelh = 0;
  for (int t = 0; t < T; t++) {
    int fr[3], fi = 0;
    for (int b = 0; b < 4; b++) if (b != cur) fr[fi++] = b;
    int bX = fr[0], bG = fr[1], bY = fr[2];
    const int* s_t = src + (size_t)t * E;
    const int* d_t = dst + (size_t)t * E;
    const int* r_t = rid + (size_t)t * E;

    mmt_step<<<1, 128, 0, stream>>>(mmtb[t & 1], l1_wih, l1_bih, l1_bhh,
                                    l2_wih, l2_bih, l2_bhh, tc_w, tc_b,
                                    mmtb[(t + 1) & 1], vbuf);
    build_M<<<H, H, 0, stream>>>(vbuf, tc_pw, MT);
    gemm_bias<<<NE / 64, 256, 0, stream>>>(B[cur], MT, tc_pb, B[bX]);
    gemm_bias<<<NR / 64, 256, 0, stream>>>(relhB[curRelh], MT, tc_pb, relhB[2]);

    // edge prep: rel bitmask + dst degree (one pass)
    hipMemsetAsync(mask, 0, (size_t)NR * MW * 4, stream);
    hipMemsetAsync(deg, 0, (size_t)NE * 4, stream);
    edge_prep<<<(E + 255) / 256, 256, 0, stream>>>(s_t, d_t, r_t, mask, deg);

    hipMemsetAsync(rel_sum, 0, ((size_t)NR * H + NR) * 4, stream);
    agg_rel_sum<<<dim3(NR, 32), 128, 0, stream>>>(mask, B[bX], rel_sum, rcnt);
    int nextRelh = 1 - curRelh;
    rel_gru<<<NR, 128, 0, stream>>>(rel_sum, rcnt, rel_embeds, relhB[2],
                                    g1_wih, g1_whh, g1_bih, g1_bhh, relhB[nextRelh]);

    scan_deg<<<1, 1024, 0, stream>>>(deg, rowptr, wpos);
    edge_fill<<<(E + 255) / 256, 256, 0, stream>>>(d_t, wpos, elist);

    // RGCN layer 0
    rgcn_gather<<<NE / 2, 256, 0, stream>>>(B[bX], relhB[nextRelh], rowptr, elist, s_t, r_t, B[bG]);
    gemm_rgcn<<<NE / 32, 256, 0, stream>>>(B[bG], B[bX], rgcn_wn, rgcn_ws, rgcn_b, deg, B[bY], 0);
    // RGCN layer 1 (+ fused row-normalize)
    rgcn_gather<<<NE / 2, 256, 0, stream>>>(B[bY], relhB[nextRelh], rowptr, elist, s_t, r_t, B[bG]);
    gemm_rgcn<<<NE / 32, 256, 0, stream>>>(B[bG], B[bY], rgcn_wn + H * H, rgcn_ws + H * H,
                                           rgcn_b + H, deg, B[cur], 1);

    gemm_update<<<NE / 64, 256, 0, stream>>>(B[bX], WTlin, lin_b, B[cur], B[bY]);

    cur = bY;
    curRelh = nextRelh;
  }

  float* entF  = B[cur];           // final entities live in d_out scratch
  float* relhF = relhB[curRelh];

  // transpose finals for the logits GEMM (FT[k][m]); pad rows zero-filled
  transposeF<<<MPE / 64, 256, 0, stream>>>(entF, FTe, NE, MPE);
  transposeF<<<NR / 64, 256, 0, stream>>>(relhF, FTr, NR, NR);

  // ConvTransE fronts: transpose weights, materialize Y, coalesced split-K GEMM
  transposeFW<<<2048, 256, 0, stream>>>(oc_fw, fwTo);
  transposeFW<<<2048, 256, 0, stream>>>(rc_fw, fwTr);

  conv_relu<<<NT / 8, 256, 0, stream>>>(entF, qsub, relhF, qrel, oc_k, oc_kb, Ybuf);
  conv_gemm<<<dim3(NT / 32, KSP), 256, 0, stream>>>(Ybuf, fwTo, Zp);
  conv_finalize<<<NT * H / 256, 256, 0, stream>>>(Zp, oc_fb, Zo);

  conv_relu<<<NT / 8, 256, 0, stream>>>(entF, qsub, entF, qobj, rc_k, rc_kb, Ybuf);
  conv_gemm<<<dim3(NT / 32, KSP), 256, 0, stream>>>(Ybuf, fwTr, Zp);
  conv_finalize<<<NT * H / 256, 256, 0, stream>>>(Zp, rc_fb, Zr);

  // logits: ent-logits with XCD swizzle (157 m-tiles -> padded to 160),
  // rel-logits plain (1 m-tile).
  int nmt = MPE / 256;                       // 157
  int grid_swz = ((nmt + 7) / 8) * 8 * 16;   // 2560
  logits_gemm3<<<grid_swz, 256, 0, stream>>>(Zo, FTe, out, NE, MPE, nmt, 1);
  logits_gemm3<<<dim3(NT / 64, NR / 256), 256, 0, stream>>>(Zr, FTr, out + (size_t)NT * NE, NR, NR, 1, 0);
}

// Round 11
// 2096.721 us; speedup vs baseline: 2.2804x; 1.1068x over previous
//
#include <hip/hip_runtime.h>
#include <cmath>

// ---------------------------------------------------------------------------
// Tconv_35450660061268 — R14 (= R13 resubmit; audit found no device fault).
//   * logits = R5's measured-best logits_gemm2 (131us); entF copied to ws
//     (entWS) since gemm2 reads F while writing out. FT path dropped.
//   * rgcn_gather: slist/rlist pre-resolved in edge_fill (2-deep chain),
//     edge loop unrolled x2.
//   * time loop + conv path = R9 (passing ancestry).
// ---------------------------------------------------------------------------

namespace {

constexpr int H   = 128;
constexpr int KK  = 4;
constexpr int C   = 32;
constexpr int NE  = 40000;
constexpr int NR  = 256;
constexpr int T   = 4;
constexpr int E   = 100000;
constexpr int NT  = 1024;
constexpr int PIN = 388;     // H*KK - H + KK
constexpr int MW  = 1280;    // mask words per relation (padded; 1250 used)
constexpr int MWU = 1250;
constexpr int KC  = 4096;    // conv GEMM K (C*H)
constexpr int KSP = 32;      // conv split-K slices (K-slice = 128)
constexpr size_t NEH = (size_t)NE * H;

__device__ __forceinline__ float sigm(float x) { return 1.0f / (1.0f + expf(-x)); }

// ---- row L2-normalize, one wave per row (init only) ------------------------
__global__ __launch_bounds__(256) void norm_rows(const float* __restrict__ in,
                                                 float* __restrict__ out, int n) {
  int row  = blockIdx.x * 4 + (threadIdx.x >> 6);
  int lane = threadIdx.x & 63;
  if (row >= n) return;
  const float2* ip = reinterpret_cast<const float2*>(in + (size_t)row * H);
  float2 v = ip[lane];
  float ss = v.x * v.x + v.y * v.y;
#pragma unroll
  for (int off = 32; off; off >>= 1) ss += __shfl_xor(ss, off);
  float inv = 1.0f / fmaxf(sqrtf(ss), 1e-12f);
  float2 o; o.x = v.x * inv; o.y = v.y * inv;
  reinterpret_cast<float2*>(out + (size_t)row * H)[lane] = o;
}

__global__ void copy_vec(const float* __restrict__ a, float* __restrict__ b, int n) {
  int i = blockIdx.x * blockDim.x + threadIdx.x;
  if (i < n) b[i] = a[i];
}

// float4 copy, n4 = count of float4 elements
__global__ __launch_bounds__(256) void copy_vec4(const float4* __restrict__ a,
                                                 float4* __restrict__ b, int n4) {
  int i = blockIdx.x * 256 + threadIdx.x;
  if (i < n4) b[i] = a[i];
}

__global__ __launch_bounds__(256) void transpose128(const float* __restrict__ in,
                                                    float* __restrict__ out) {
  int i = blockIdx.x * 256 + threadIdx.x;   // grid 64
  int o = i >> 7, k = i & 127;
  out[k * H + o] = in[o * H + k];
}

// fwT[k*128 + o] = fw[o*4096 + k]   (128 x 4096 -> 4096 x 128), grid 2048
__global__ __launch_bounds__(256) void transposeFW(const float* __restrict__ in,
                                                   float* __restrict__ out) {
  int i = blockIdx.x * 256 + threadIdx.x;
  int o = i >> 12, k = i & 4095;
  out[(size_t)k * 128 + o] = in[i];
}

// ---- mmt GRU pair + gated update + v = mmt_new @ tc_w^T + tc_b (1 block) ---
__global__ __launch_bounds__(128) void mmt_step(
    const float* __restrict__ mmt_in,
    const float* __restrict__ w1, const float* __restrict__ bi1, const float* __restrict__ bh1,
    const float* __restrict__ w2, const float* __restrict__ bi2, const float* __restrict__ bh2,
    const float* __restrict__ tcw, const float* __restrict__ tcb,
    float* __restrict__ mmt_out, float* __restrict__ vout) {
  __shared__ float sm[H], sm2[H];
  int t = threadIdx.x;
  sm[t] = mmt_in[t];
  __syncthreads();
  float g1r = bi1[t], g1z = bi1[H + t], g1n = bi1[2 * H + t];
  float g2r = bi2[t], g2z = bi2[H + t], g2n = bi2[2 * H + t];
  {
    const float4* r1p = reinterpret_cast<const float4*>(w1 + (size_t)t * H);
    const float4* z1p = reinterpret_cast<const float4*>(w1 + (size_t)(H + t) * H);
    const float4* n1p = reinterpret_cast<const float4*>(w1 + (size_t)(2 * H + t) * H);
    const float4* r2p = reinterpret_cast<const float4*>(w2 + (size_t)t * H);
    const float4* z2p = reinterpret_cast<const float4*>(w2 + (size_t)(H + t) * H);
    const float4* n2p = reinterpret_cast<const float4*>(w2 + (size_t)(2 * H + t) * H);
    const float4* x4 = reinterpret_cast<const float4*>(sm);
    for (int k = 0; k < 32; k++) {
      float4 x = x4[k];
      float4 a = r1p[k], b = z1p[k], c = n1p[k], d = r2p[k], e = z2p[k], f = n2p[k];
      g1r += x.x * a.x + x.y * a.y + x.z * a.z + x.w * a.w;
      g1z += x.x * b.x + x.y * b.y + x.z * b.z + x.w * b.w;
      g1n += x.x * c.x + x.y * c.y + x.z * c.z + x.w * c.w;
      g2r += x.x * d.x + x.y * d.y + x.z * d.z + x.w * d.w;
      g2z += x.x * e.x + x.y * e.y + x.z * e.z + x.w * e.w;
      g2n += x.x * f.x + x.y * f.y + x.z * f.z + x.w * f.w;
    }
  }
  float r1 = sigm(g1r + bh1[t]), z1 = sigm(g1z + bh1[H + t]);
  float n1 = tanhf(g1n + r1 * bh1[2 * H + t]);
  float nmmt = (1.0f - z1) * n1;
  float r2 = sigm(g2r + bh2[t]), z2 = sigm(g2z + bh2[H + t]);
  float n2 = tanhf(g2n + r2 * bh2[2 * H + t]);
  float gg = (1.0f - z2) * n2;
  float m  = sm[t];
  float mo = m + gg * (nmmt - m);
  mmt_out[t] = mo;
  sm2[t] = mo;
  __syncthreads();
  float v = tcb[t];
  {
    const float4* wp = reinterpret_cast<const float4*>(tcw + (size_t)t * H);
    const float4* x4 = reinterpret_cast<const float4*>(sm2);
    for (int k = 0; k < 32; k++) {
      float4 x = x4[k], w = wp[k];
      v += x.x * w.x + x.y * w.y + x.z * w.z + x.w * w.w;
    }
  }
  vout[t] = v;
}

// ---- build MT[p*H+o] = M[o][p] (k-major tconv map) -------------------------
__global__ __launch_bounds__(128) void build_M(const float* __restrict__ v,
                                               const float* __restrict__ pw,
                                               float* __restrict__ MT) {
  int o = blockIdx.x, p = threadIdx.x;
  __shared__ float sp[PIN];
  __shared__ float sv[H];
  for (int i = p; i < PIN; i += H) sp[i] = pw[(size_t)o * PIN + i];
  sv[p] = v[p];
  __syncthreads();
  float acc = 0.0f;
  int jlo = p - 31 > 0 ? p - 31 : 0;
  int jhi = p < 96 ? p : 96;
#pragma unroll
  for (int k = 0; k < KK; k++)
    for (int j = jlo; j <= jhi; j++) acc += sp[k * 97 + j] * sv[k * 32 + (p - j)];
  MT[p * H + o] = acc;
}

// ===========================================================================
// Register-tiled GEMM family (unchanged core from R2).
// ===========================================================================
__global__ __launch_bounds__(256) void gemm_bias(const float* __restrict__ X,
                                                 const float* __restrict__ WT,
                                                 const float* __restrict__ bias,
                                                 float* __restrict__ out) {
  __shared__ float sX[64 * H];
  int t = threadIdx.x;
  int base = blockIdx.x * 64;
  const float4* gx = reinterpret_cast<const float4*>(X + (size_t)base * H);
  float4* sx4 = reinterpret_cast<float4*>(sX);
#pragma unroll
  for (int i = 0; i < 8; i++) sx4[t + 256 * i] = gx[t + 256 * i];
  __syncthreads();
  int oq = (t & 31) * 4, ng = (t >> 5) * 8;
  float acc[8][4] = {};
  for (int k = 0; k < H; k += 4) {
    float4 w0 = *reinterpret_cast<const float4*>(&WT[(k + 0) * H + oq]);
    float4 w1 = *reinterpret_cast<const float4*>(&WT[(k + 1) * H + oq]);
    float4 w2 = *reinterpret_cast<const float4*>(&WT[(k + 2) * H + oq]);
    float4 w3 = *reinterpret_cast<const float4*>(&WT[(k + 3) * H + oq]);
#pragma unroll
    for (int m = 0; m < 8; m++) {
      float4 x = *reinterpret_cast<const float4*>(&sX[(ng + m) * H + k]);
      acc[m][0] += x.x * w0.x + x.y * w1.x + x.z * w2.x + x.w * w3.x;
      acc[m][1] += x.x * w0.y + x.y * w1.y + x.z * w2.y + x.w * w3.y;
      acc[m][2] += x.x * w0.z + x.y * w1.z + x.z * w2.z + x.w * w3.z;
      acc[m][3] += x.x * w0.w + x.y * w1.w + x.z * w2.w + x.w * w3.w;
    }
  }
  float4 b4 = *reinterpret_cast<const float4*>(&bias[oq]);
#pragma unroll
  for (int m = 0; m < 8; m++) {
    float4 o4 = {acc[m][0] + b4.x, acc[m][1] + b4.y, acc[m][2] + b4.z, acc[m][3] + b4.w};
    *reinterpret_cast<float4*>(&out[(size_t)(base + ng + m) * H + oq]) = o4;
  }
}

// RGCN layer fused: out = relu((A@wn)*inv_deg + Hm@ws + b); optional row-norm.
__global__ __launch_bounds__(256) void gemm_rgcn(const float* __restrict__ A,
                                                 const float* __restrict__ Hm,
                                                 const float* __restrict__ wn,
                                                 const float* __restrict__ ws,
                                                 const float* __restrict__ bias,
                                                 const int* __restrict__ deg,
                                                 float* __restrict__ out,
                                                 int donorm) {
  __shared__ float sA[32 * H];
  __shared__ float sH[32 * H];
  int t = threadIdx.x;
  int base = blockIdx.x * 32;
  const float4* ga = reinterpret_cast<const float4*>(A + (size_t)base * H);
  const float4* gh = reinterpret_cast<const float4*>(Hm + (size_t)base * H);
  float4* sa4 = reinterpret_cast<float4*>(sA);
  float4* sh4 = reinterpret_cast<float4*>(sH);
#pragma unroll
  for (int i = 0; i < 4; i++) { sa4[t + 256 * i] = ga[t + 256 * i]; sh4[t + 256 * i] = gh[t + 256 * i]; }
  __syncthreads();
  int oq = (t & 31) * 4, ng = (t >> 5) * 4;
  float accA[4][4] = {}, accS[4][4] = {};
  for (int k = 0; k < H; k += 4) {
    float4 n0 = *reinterpret_cast<const float4*>(&wn[(k + 0) * H + oq]);
    float4 n1 = *reinterpret_cast<const float4*>(&wn[(k + 1) * H + oq]);
    float4 n2 = *reinterpret_cast<const float4*>(&wn[(k + 2) * H + oq]);
    float4 n3 = *reinterpret_cast<const float4*>(&wn[(k + 3) * H + oq]);
    float4 s0 = *reinterpret_cast<const float4*>(&ws[(k + 0) * H + oq]);
    float4 s1 = *reinterpret_cast<const float4*>(&ws[(k + 1) * H + oq]);
    float4 s2 = *reinterpret_cast<const float4*>(&ws[(k + 2) * H + oq]);
    float4 s3 = *reinterpret_cast<const float4*>(&ws[(k + 3) * H + oq]);
#pragma unroll
    for (int m = 0; m < 4; m++) {
      float4 a = *reinterpret_cast<const float4*>(&sA[(ng + m) * H + k]);
      float4 h = *reinterpret_cast<const float4*>(&sH[(ng + m) * H + k]);
      accA[m][0] += a.x * n0.x + a.y * n1.x + a.z * n2.x + a.w * n3.x;
      accA[m][1] += a.x * n0.y + a.y * n1.y + a.z * n2.y + a.w * n3.y;
      accA[m][2] += a.x * n0.z + a.y * n1.z + a.z * n2.z + a.w * n3.z;
      accA[m][3] += a.x * n0.w + a.y * n1.w + a.z * n2.w + a.w * n3.w;
      accS[m][0] += h.x * s0.x + h.y * s1.x + h.z * s2.x + h.w * s3.x;
      accS[m][1] += h.x * s0.y + h.y * s1.y + h.z * s2.y + h.w * s3.y;
      accS[m][2] += h.x * s0.z + h.y * s1.z + h.z * s2.z + h.w * s3.z;
      accS[m][3] += h.x * s0.w + h.y * s1.w + h.z * s2.w + h.w * s3.w;
    }
  }
  float4 b4 = *reinterpret_cast<const float4*>(&bias[oq]);
  float v[4][4];
#pragma unroll
  for (int m = 0; m < 4; m++) {
    float inv = 1.0f / fmaxf((float)deg[base + ng + m], 1.0f);
    v[m][0] = fmaxf(accA[m][0] * inv + accS[m][0] + b4.x, 0.0f);
    v[m][1] = fmaxf(accA[m][1] * inv + accS[m][1] + b4.y, 0.0f);
    v[m][2] = fmaxf(accA[m][2] * inv + accS[m][2] + b4.z, 0.0f);
    v[m][3] = fmaxf(accA[m][3] * inv + accS[m][3] + b4.w, 0.0f);
  }
  if (donorm) {
#pragma unroll
    for (int m = 0; m < 4; m++) {
      float ss = v[m][0]*v[m][0] + v[m][1]*v[m][1] + v[m][2]*v[m][2] + v[m][3]*v[m][3];
#pragma unroll
      for (int off = 16; off; off >>= 1) ss += __shfl_xor(ss, off);
      float inv = 1.0f / fmaxf(sqrtf(ss), 1e-12f);
      v[m][0] *= inv; v[m][1] *= inv; v[m][2] *= inv; v[m][3] *= inv;
    }
  }
#pragma unroll
  for (int m = 0; m < 4; m++) {
    float4 o4 = {v[m][0], v[m][1], v[m][2], v[m][3]};
    *reinterpret_cast<float4*>(&out[(size_t)(base + ng + m) * H + oq]) = o4;
  }
}

// out = e + sigm(e@WT+b)*(nf - e)
__global__ __launch_bounds__(256) void gemm_update(const float* __restrict__ Xe,
                                                   const float* __restrict__ WT,
                                                   const float* __restrict__ bias,
                                                   const float* __restrict__ nf,
                                                   float* __restrict__ out) {
  __shared__ float sX[64 * H];
  int t = threadIdx.x;
  int base = blockIdx.x * 64;
  const float4* gx = reinterpret_cast<const float4*>(Xe + (size_t)base * H);
  float4* sx4 = reinterpret_cast<float4*>(sX);
#pragma unroll
  for (int i = 0; i < 8; i++) sx4[t + 256 * i] = gx[t + 256 * i];
  __syncthreads();
  int oq = (t & 31) * 4, ng = (t >> 5) * 8;
  float acc[8][4] = {};
  for (int k = 0; k < H; k += 4) {
    float4 w0 = *reinterpret_cast<const float4*>(&WT[(k + 0) * H + oq]);
    float4 w1 = *reinterpret_cast<const float4*>(&WT[(k + 1) * H + oq]);
    float4 w2 = *reinterpret_cast<const float4*>(&WT[(k + 2) * H + oq]);
    float4 w3 = *reinterpret_cast<const float4*>(&WT[(k + 3) * H + oq]);
#pragma unroll
    for (int m = 0; m < 8; m++) {
      float4 x = *reinterpret_cast<const float4*>(&sX[(ng + m) * H + k]);
      acc[m][0] += x.x * w0.x + x.y * w1.x + x.z * w2.x + x.w * w3.x;
      acc[m][1] += x.x * w0.y + x.y * w1.y + x.z * w2.y + x.w * w3.y;
      acc[m][2] += x.x * w0.z + x.y * w1.z + x.z * w2.z + x.w * w3.z;
      acc[m][3] += x.x * w0.w + x.y * w1.w + x.z * w2.w + x.w * w3.w;
    }
  }
  float4 b4 = *reinterpret_cast<const float4*>(&bias[oq]);
#pragma unroll
  for (int m = 0; m < 8; m++) {
    size_t row = (size_t)(base + ng + m) * H;
    float4 e4 = *reinterpret_cast<const float4*>(&sX[(ng + m) * H + oq]);
    float4 f4 = *reinterpret_cast<const float4*>(&nf[row + oq]);
    float4 o4 = {e4.x + sigm(acc[m][0] + b4.x) * (f4.x - e4.x),
                 e4.y + sigm(acc[m][1] + b4.y) * (f4.y - e4.y),
                 e4.z + sigm(acc[m][2] + b4.z) * (f4.z - e4.z),
                 e4.w + sigm(acc[m][3] + b4.w) * (f4.w - e4.w)};
    *reinterpret_cast<float4*>(&out[row + oq]) = o4;
  }
}

// ===========================================================================
// Edge prep: rel-bitmask scatter + dst-degree histogram in one pass over E.
// ===========================================================================
__global__ __launch_bounds__(256) void edge_prep(const int* __restrict__ s,
                                                 const int* __restrict__ d,
                                                 const int* __restrict__ r,
                                                 unsigned int* __restrict__ mask,
                                                 int* __restrict__ deg) {
  int e = blockIdx.x * 256 + threadIdx.x;
  if (e >= E) return;
  int ri = r[e], si = s[e], di = d[e];
  atomicOr(&mask[(size_t)ri * MW + (si >> 5)], 1u << (si & 31));
  atomicOr(&mask[(size_t)ri * MW + (di >> 5)], 1u << (di & 31));
  atomicAdd(&deg[di], 1);
}

// wave-shfl scan over deg -> rowptr (exclusive) + wpos copy
__global__ __launch_bounds__(1024) void scan_deg(const int* __restrict__ deg,
                                                 int* __restrict__ rowptr,
                                                 int* __restrict__ wpos) {
  __shared__ int wsum[16];
  __shared__ int carry_s;
  int tid = threadIdx.x, lane = tid & 63, w = tid >> 6;
  if (tid == 0) carry_s = 0;
  __syncthreads();
  for (int base = 0; base < NE; base += 1024) {
    int idx = base + tid;
    int v = idx < NE ? deg[idx] : 0;
    int x = v;
#pragma unroll
    for (int off = 1; off < 64; off <<= 1) {
      int y = __shfl_up(x, off, 64);
      if (lane >= off) x += y;
    }
    if (lane == 63) wsum[w] = x;
    __syncthreads();
    int carry = carry_s;
    int wpre = 0;
    for (int i = 0; i < w; i++) wpre += wsum[i];
    int excl = carry + wpre + x - v;
    if (idx < NE) { rowptr[idx] = excl; wpos[idx] = excl; }
    __syncthreads();
    if (tid == 1023) carry_s = carry + wpre + x;
  }
  __syncthreads();
  if (tid == 0) rowptr[NE] = carry_s;
}

// CSR fill with pre-resolved src/rel (drops one indirection in the gather)
__global__ __launch_bounds__(256) void edge_fill(const int* __restrict__ s,
                                                 const int* __restrict__ d,
                                                 const int* __restrict__ r,
                                                 int* __restrict__ wpos,
                                                 int* __restrict__ slist,
                                                 int* __restrict__ rlist) {
  int e = blockIdx.x * 256 + threadIdx.x;
  if (e >= E) return;
  int p = atomicAdd(&wpos[d[e]], 1);
  slist[p] = s[e];
  rlist[p] = r[e];
}

// agg[n][dim] = sum_{e: d[e]==n} h[s][dim] + ef[r][dim]   (2 nodes/blk)
// slist/rlist pre-resolved; unrolled x2 for 4 row-gathers in flight.
__global__ __launch_bounds__(256) void rgcn_gather(const float* __restrict__ h,
                                                   const float* __restrict__ ef,
                                                   const int* __restrict__ rowptr,
                                                   const int* __restrict__ slist,
                                                   const int* __restrict__ rlist,
                                                   float* __restrict__ agg) {
  int node = blockIdx.x * 2 + (threadIdx.x >> 7);
  int dim  = threadIdx.x & 127;
  int b = rowptr[node], e2 = rowptr[node + 1];
  float acc = 0.0f;
  int i = b;
  for (; i + 1 < e2; i += 2) {
    int s0 = slist[i], r0 = rlist[i];
    int s1 = slist[i + 1], r1 = rlist[i + 1];
    float a0 = h[(size_t)s0 * H + dim];
    float b0 = ef[(size_t)r0 * H + dim];
    float a1 = h[(size_t)s1 * H + dim];
    float b1 = ef[(size_t)r1 * H + dim];
    acc += a0 + b0 + a1 + b1;
  }
  if (i < e2) {
    acc += h[(size_t)slist[i] * H + dim] + ef[(size_t)rlist[i] * H + dim];
  }
  agg[(size_t)node * H + dim] = acc;
}

// ---- _agg_rel masked sum: 32 partitions per relation -----------------------
__global__ __launch_bounds__(128) void agg_rel_sum(const unsigned int* __restrict__ mask,
                                                   const float* __restrict__ ent,
                                                   float* __restrict__ rsum,
                                                   float* __restrict__ rcnt) {
  int rel = blockIdx.x, part = blockIdx.y, tid = threadIdx.x;
  const int WPS = (MWU + 31) / 32;  // 40
  int w0 = part * WPS;
  int w1 = w0 + WPS < MWU ? w0 + WPS : MWU;
  float acc = 0.0f, cnt = 0.0f;
  const unsigned int* mrow = mask + (size_t)rel * MW;
  for (int w = w0; w < w1; w++) {
    unsigned int bits = mrow[w];
    if (!bits) continue;
    cnt += (float)__popc(bits);
    int base = w << 5;
    while (bits) {
      int b = __ffs(bits) - 1;
      bits &= bits - 1;
      acc += ent[(size_t)(base + b) * H + tid];
    }
  }
  if (acc != 0.0f) atomicAdd(&rsum[rel * H + tid], acc);
  if (tid == 0 && cnt != 0.0f) atomicAdd(&rcnt[rel], cnt);
}

// ---- relation GRU (finalize fused) + row normalize -------------------------
__global__ __launch_bounds__(128) void rel_gru(const float* __restrict__ rsum,
                                               const float* __restrict__ rcnt,
                                               const float* __restrict__ rel_param,
                                               const float* __restrict__ relh,
                                               const float* __restrict__ wih,
                                               const float* __restrict__ whh,
                                               const float* __restrict__ bih,
                                               const float* __restrict__ bhh,
                                               float* __restrict__ outp) {
  int rel = blockIdx.x, tid = threadIdx.x;
  __shared__ float sx[2 * H], sh[H], red[H];
  float c = rcnt[rel];
  sx[tid]     = c > 0.0f ? rsum[rel * H + tid] / fmaxf(c, 1.0f) : 0.0f;
  sx[H + tid] = rel_param[rel * H + tid];
  sh[tid]     = relh[rel * H + tid];
  __syncthreads();
  float gr = bih[tid], gz = bih[H + tid], gn = bih[2 * H + tid];
  {
    const float4* rp = reinterpret_cast<const float4*>(wih + (size_t)tid * 2 * H);
    const float4* zp = reinterpret_cast<const float4*>(wih + (size_t)(H + tid) * 2 * H);
    const float4* np = reinterpret_cast<const float4*>(wih + (size_t)(2 * H + tid) * 2 * H);
    const float4* x4 = reinterpret_cast<const float4*>(sx);
    for (int k = 0; k < 64; k++) {
      float4 x = x4[k];
      float4 a = rp[k], b = zp[k], cc = np[k];
      gr += x.x * a.x + x.y * a.y + x.z * a.z + x.w * a.w;
      gz += x.x * b.x + x.y * b.y + x.z * b.z + x.w * b.w;
      gn += x.x * cc.x + x.y * cc.y + x.z * cc.z + x.w * cc.w;
    }
  }
  float hr = bhh[tid], hz = bhh[H + tid], hn = bhh[2 * H + tid];
  {
    const float4* rp = reinterpret_cast<const float4*>(whh + (size_t)tid * H);
    const float4* zp = reinterpret_cast<const float4*>(whh + (size_t)(H + tid) * H);
    const float4* np = reinterpret_cast<const float4*>(whh + (size_t)(2 * H + tid) * H);
    const float4* h4 = reinterpret_cast<const float4*>(sh);
    for (int k = 0; k < 32; k++) {
      float4 x = h4[k];
      float4 a = rp[k], b = zp[k], cc = np[k];
      hr += x.x * a.x + x.y * a.y + x.z * a.z + x.w * a.w;
      hz += x.x * b.x + x.y * b.y + x.z * b.z + x.w * b.w;
      hn += x.x * cc.x + x.y * cc.y + x.z * cc.z + x.w * cc.w;
    }
  }
  float r = sigm(gr + hr), z = sigm(gz + hz), nn = tanhf(gn + r * hn);
  float val = (1.0f - z) * nn + z * sh[tid];
  red[tid] = val * val;
  __syncthreads();
  for (int s2 = 64; s2 > 0; s2 >>= 1) {
    if (tid < s2) red[tid] += red[tid + s2];
    __syncthreads();
  }
  float inv = 1.0f / fmaxf(sqrtf(red[0]), 1e-12f);
  outp[rel * H + tid] = val * inv;
}

// ===========================================================================
// ConvTransE front — stage A: materialize Y[NT][4096] = relu(conv(x)).
// ===========================================================================
__global__ __launch_bounds__(256) void conv_relu(const float* __restrict__ fa,
                                                 const int* __restrict__ ia,
                                                 const float* __restrict__ fbm,
                                                 const int* __restrict__ ib,
                                                 const float* __restrict__ ck,
                                                 const float* __restrict__ ckb,
                                                 float* __restrict__ Y) {
  __shared__ float sx[8 * 2 * H];   // 8 KB
  __shared__ float sck[C * 6];
  __shared__ float sckb[C];
  int tid = threadIdx.x, q0 = blockIdx.x * 8;
  if (tid < C * 6) sck[tid] = ck[tid];
  if (tid < C)     sckb[tid] = ckb[tid];
#pragma unroll
  for (int i = tid; i < 2048; i += 256) {
    int q = i >> 8, half = (i >> 7) & 1, p = i & 127;
    int node = (half ? ib : ia)[q0 + q];
    sx[i] = (half ? fbm : fa)[(size_t)node * H + p];
  }
  __syncthreads();
  for (int i4 = tid; i4 < 8192; i4 += 256) {
    int q = i4 >> 10, rr = i4 & 1023;
    int c = rr >> 5, p0 = (rr & 31) << 2;
    const float* x0 = &sx[q * 256];
    const float* x1 = x0 + 128;
    float k00 = sck[c * 6 + 0], k01 = sck[c * 6 + 1], k02 = sck[c * 6 + 2];
    float k10 = sck[c * 6 + 3], k11 = sck[c * 6 + 4], k12 = sck[c * 6 + 5];
    float bb = sckb[c];
    float4 o;
    float* op = &o.x;
#pragma unroll
    for (int dd = 0; dd < 4; dd++) {
      int p = p0 + dd;
      float acc = bb + x0[p] * k01 + x1[p] * k11;
      if (p - 1 >= 0)  acc += x0[p - 1] * k00 + x1[p - 1] * k10;
      if (p + 1 < H)   acc += x0[p + 1] * k02 + x1[p + 1] * k12;
      op[dd] = fmaxf(acc, 0.0f);
    }
    *reinterpret_cast<float4*>(&Y[(size_t)(q0 + q) * KC + rr * 4]) = o;
  }
}

// ===========================================================================
// ConvTransE front — stage B: split-K GEMM, Zp[ks] = Y[:,ksl] @ fwT[ksl,:].
// ===========================================================================
__global__ __launch_bounds__(256) void conv_gemm(const float* __restrict__ Y,
                                                 const float* __restrict__ fwT,
                                                 float* __restrict__ Zp) {
  int t = threadIdx.x;
  int mb = blockIdx.x * 32, ks = blockIdx.y;
  int oq = (t & 31) * 4, ng = (t >> 5) * 4;
  const float* yb = Y + (size_t)(mb + ng) * KC + ks * 128;
  const float* wb = fwT + (size_t)ks * 128 * H + oq;
  float acc[4][4] = {};
  for (int k = 0; k < 128; k += 4) {
    float4 w0 = *reinterpret_cast<const float4*>(wb + (size_t)(k + 0) * H);
    float4 w1 = *reinterpret_cast<const float4*>(wb + (size_t)(k + 1) * H);
    float4 w2 = *reinterpret_cast<const float4*>(wb + (size_t)(k + 2) * H);
    float4 w3 = *reinterpret_cast<const float4*>(wb + (size_t)(k + 3) * H);
#pragma unroll
    for (int m = 0; m < 4; m++) {
      float4 y = *reinterpret_cast<const float4*>(yb + (size_t)m * KC + k);
      acc[m][0] += y.x * w0.x + y.y * w1.x + y.z * w2.x + y.w * w3.x;
      acc[m][1] += y.x * w0.y + y.y * w1.y + y.z * w2.y + y.w * w3.y;
      acc[m][2] += y.x * w0.z + y.y * w1.z + y.z * w2.z + y.w * w3.z;
      acc[m][3] += y.x * w0.w + y.y * w1.w + y.z * w2.w + y.w * w3.w;
    }
  }
  float* zb = Zp + (size_t)ks * NT * H;
#pragma unroll
  for (int m = 0; m < 4; m++) {
    float4 o4 = {acc[m][0], acc[m][1], acc[m][2], acc[m][3]};
    *reinterpret_cast<float4*>(&zb[(size_t)(mb + ng + m) * H + oq]) = o4;
  }
}

__global__ __launch_bounds__(256) void conv_finalize(const float* __restrict__ Zp,
                                                     const float* __restrict__ fb,
                                                     float* __restrict__ Z) {
  int i = blockIdx.x * 256 + threadIdx.x;  // NT*H / 256
  int o = i & 127;
  float v = fb[o];
#pragma unroll
  for (int s = 0; s < KSP; s++) v += Zp[(size_t)s * NT * H + i];
  Z[i] = fmaxf(v, 0.0f);
}

// ---- logits: 128x128 tile, Kc=32, 8x8/thread (R5's measured-best) ----------
__global__ __launch_bounds__(256) void logits_gemm2(const float* __restrict__ Z,
                                                    const float* __restrict__ F,
                                                    float* __restrict__ out,
                                                    int M) {
  __shared__ float sZ[32 * H];
  __shared__ float sF[32 * H];
  int t = threadIdx.x;
  int bq = blockIdx.y * 128, bm = blockIdx.x * 128;
  int tx = t & 15, ty = t >> 4;
  float acc[8][8] = {};
  int qld = t & 127, kh = (t >> 7) * 16;
  int mld = bm + qld;
  if (mld >= M) mld = M - 1;
  for (int kc = 0; kc < H; kc += 32) {
    __syncthreads();
    const float* zr = Z + (size_t)(bq + qld) * H + kc + kh;
    const float* fr = F + (size_t)mld * H + kc + kh;
#pragma unroll
    for (int j = 0; j < 16; j += 4) {
      float4 v = *reinterpret_cast<const float4*>(zr + j);
      sZ[(kh + j + 0) * H + qld] = v.x;
      sZ[(kh + j + 1) * H + qld] = v.y;
      sZ[(kh + j + 2) * H + qld] = v.z;
      sZ[(kh + j + 3) * H + qld] = v.w;
      float4 f = *reinterpret_cast<const float4*>(fr + j);
      sF[(kh + j + 0) * H + qld] = f.x;
      sF[(kh + j + 1) * H + qld] = f.y;
      sF[(kh + j + 2) * H + qld] = f.z;
      sF[(kh + j + 3) * H + qld] = f.w;
    }
    __syncthreads();
    for (int k = 0; k < 32; k++) {
      float4 za = *reinterpret_cast<const float4*>(&sZ[k * H + ty * 8]);
      float4 zb = *reinterpret_cast<const float4*>(&sZ[k * H + ty * 8 + 4]);
      float4 fa = *reinterpret_cast<const float4*>(&sF[k * H + tx * 8]);
      float4 fbv = *reinterpret_cast<const float4*>(&sF[k * H + tx * 8 + 4]);
      float zq[8] = {za.x, za.y, za.z, za.w, zb.x, zb.y, zb.z, zb.w};
      float fm[8] = {fa.x, fa.y, fa.z, fa.w, fbv.x, fbv.y, fbv.z, fbv.w};
#pragma unroll
      for (int i = 0; i < 8; i++)
#pragma unroll
        for (int j = 0; j < 8; j++) acc[i][j] += zq[i] * fm[j];
    }
  }
  int m0 = bm + tx * 8;
  if (m0 >= M) return;
#pragma unroll
  for (int i = 0; i < 8; i++) {
    size_t row = (size_t)(bq + ty * 8 + i) * (size_t)M + m0;
    float4 o1 = {acc[i][0], acc[i][1], acc[i][2], acc[i][3]};
    float4 o2 = {acc[i][4], acc[i][5], acc[i][6], acc[i][7]};
    *reinterpret_cast<float4*>(&out[row]) = o1;
    *reinterpret_cast<float4*>(&out[row + 4]) = o2;
  }
}

}  // namespace

extern "C" void kernel_launch(void* const* d_in, const int* in_sizes, int n_in,
                              void* d_out, int out_size, void* d_ws, size_t ws_size,
                              hipStream_t stream) {
  (void)in_sizes; (void)n_in; (void)out_size; (void)ws_size;
  const float* ent_embeds = (const float*)d_in[0];
  const float* rel_embeds = (const float*)d_in[1];
  const float* mmt_embed  = (const float*)d_in[2];
  const float* tc_w  = (const float*)d_in[3];
  const float* tc_b  = (const float*)d_in[4];
  const float* tc_pw = (const float*)d_in[5];
  const float* tc_pb = (const float*)d_in[6];
  const float* g1_wih = (const float*)d_in[7];
  const float* g1_whh = (const float*)d_in[8];
  const float* g1_bih = (const float*)d_in[9];
  const float* g1_bhh = (const float*)d_in[10];
  const float* l1_wih = (const float*)d_in[11];
  const float* l1_bih = (const float*)d_in[13];
  const float* l1_bhh = (const float*)d_in[14];
  const float* l2_wih = (const float*)d_in[15];
  const float* l2_bih = (const float*)d_in[17];
  const float* l2_bhh = (const float*)d_in[18];
  const float* lin_w = (const float*)d_in[19];
  const float* lin_b = (const float*)d_in[20];
  const float* rgcn_wn = (const float*)d_in[21];
  const float* rgcn_ws = (const float*)d_in[22];
  const float* rgcn_b  = (const float*)d_in[23];
  const float* oc_k  = (const float*)d_in[24];
  const float* oc_kb = (const float*)d_in[25];
  const float* oc_fw = (const float*)d_in[26];
  const float* oc_fb = (const float*)d_in[27];
  const float* rc_k  = (const float*)d_in[28];
  const float* rc_kb = (const float*)d_in[29];
  const float* rc_fw = (const float*)d_in[30];
  const float* rc_fb = (const float*)d_in[31];
  const int* src  = (const int*)d_in[32];
  const int* dst  = (const int*)d_in[33];
  const int* rid  = (const int*)d_in[34];
  const int* qsub = (const int*)d_in[35];
  const int* qrel = (const int*)d_in[36];
  const int* qobj = (const int*)d_in[37];

  float* out = (float*)d_out;
  float* ws  = (float*)d_ws;

  // ---- d_ws layout (floats) — footprint <= R9-R12 (entWS replaces FTe+FTr)
  size_t off = 0;
  float* relhB[3] = {ws + off, ws + off + (size_t)NR * H, ws + off + 2 * (size_t)NR * H};
  off += 3 * (size_t)NR * H;
  float* rel_sum = ws + off; off += (size_t)NR * H;
  float* rcnt    = ws + off; off += NR;
  float* mmtbuf0 = ws + off; off += H;
  float* mmtbuf1 = ws + off; off += H;
  float* vbuf    = ws + off; off += H;
  float* MT      = ws + off; off += (size_t)H * H;
  float* WTlin   = ws + off; off += (size_t)H * H;
  float* Zo      = ws + off; off += (size_t)NT * H;
  float* Zr      = ws + off; off += (size_t)NT * H;
  float* entWS   = ws + off; off += NEH;                 // row-major entF copy for logits
  unsigned int* mask = (unsigned int*)(ws + off); off += (size_t)NR * MW;

  // ---- d_out as scratch: 4 rotating NE*H buffers + CSR ints in the tail ----
  float* B[4] = {out, out + NEH, out + 2 * NEH, out + 3 * NEH};
  int* itail   = (int*)(out + 4 * NEH);
  int* deg     = itail;
  int* rowptr  = itail + NE;
  int* wpos    = itail + 2 * NE + 1;
  int* slist   = itail + 3 * NE + 1;
  int* rlist   = slist + E;
  float* mmtb[2] = {mmtbuf0, mmtbuf1};
  // conv scratch (dead before logits write out). All below 10.24M floats;
  // final entities end up in B[2] = [10.24M, 15.36M) — no overlap.
  float* Ybuf  = out;                                     // [0, 4.19M)
  float* Zp    = out + (size_t)NT * KC;                   // [4.19M, 8.39M)
  float* fwTo  = Zp + (size_t)KSP * NT * H;               // [8.39M, 8.91M)
  float* fwTr  = fwTo + (size_t)KC * H;                   // [8.91M, 9.44M)

  norm_rows<<<(NE + 3) / 4, 256, 0, stream>>>(ent_embeds, B[0], NE);
  norm_rows<<<(NR + 3) / 4, 256, 0, stream>>>(rel_embeds, relhB[0], NR);
  copy_vec<<<1, 128, 0, stream>>>(mmt_embed, mmtbuf0, H);
  transpose128<<<64, 256, 0, stream>>>(lin_w, WTlin);

  int cur = 0, curRelh = 0;
  for (int t = 0; t < T; t++) {
    int fr[3], fi = 0;
    for (int b = 0; b < 4; b++) if (b != cur) fr[fi++] = b;
    int bX = fr[0], bG = fr[1], bY = fr[2];
    const int* s_t = src + (size_t)t * E;
    const int* d_t = dst + (size_t)t * E;
    const int* r_t = rid + (size_t)t * E;

    mmt_step<<<1, 128, 0, stream>>>(mmtb[t & 1], l1_wih, l1_bih, l1_bhh,
                                    l2_wih, l2_bih, l2_bhh, tc_w, tc_b,
                                    mmtb[(t + 1) & 1], vbuf);
    build_M<<<H, H, 0, stream>>>(vbuf, tc_pw, MT);
    gemm_bias<<<NE / 64, 256, 0, stream>>>(B[cur], MT, tc_pb, B[bX]);
    gemm_bias<<<NR / 64, 256, 0, stream>>>(relhB[curRelh], MT, tc_pb, relhB[2]);

    // edge prep: rel bitmask + dst degree (one pass)
    hipMemsetAsync(mask, 0, (size_t)NR * MW * 4, stream);
    hipMemsetAsync(deg, 0, (size_t)NE * 4, stream);
    edge_prep<<<(E + 255) / 256, 256, 0, stream>>>(s_t, d_t, r_t, mask, deg);

    hipMemsetAsync(rel_sum, 0, ((size_t)NR * H + NR) * 4, stream);
    agg_rel_sum<<<dim3(NR, 32), 128, 0, stream>>>(mask, B[bX], rel_sum, rcnt);
    int nextRelh = 1 - curRelh;
    rel_gru<<<NR, 128, 0, stream>>>(rel_sum, rcnt, rel_embeds, relhB[2],
                                    g1_wih, g1_whh, g1_bih, g1_bhh, relhB[nextRelh]);

    scan_deg<<<1, 1024, 0, stream>>>(deg, rowptr, wpos);
    edge_fill<<<(E + 255) / 256, 256, 0, stream>>>(s_t, d_t, r_t, wpos, slist, rlist);

    // RGCN layer 0
    rgcn_gather<<<NE / 2, 256, 0, stream>>>(B[bX], relhB[nextRelh], rowptr, slist, rlist, B[bG]);
    gemm_rgcn<<<NE / 32, 256, 0, stream>>>(B[bG], B[bX], rgcn_wn, rgcn_ws, rgcn_b, deg, B[bY], 0);
    // RGCN layer 1 (+ fused row-normalize)
    rgcn_gather<<<NE / 2, 256, 0, stream>>>(B[bY], relhB[nextRelh], rowptr, slist, rlist, B[bG]);
    gemm_rgcn<<<NE / 32, 256, 0, stream>>>(B[bG], B[bY], rgcn_wn + H * H, rgcn_ws + H * H,
                                           rgcn_b + H, deg, B[cur], 1);

    gemm_update<<<NE / 64, 256, 0, stream>>>(B[bX], WTlin, lin_b, B[cur], B[bY]);

    cur = bY;
    curRelh = nextRelh;
  }

  float* entF  = B[cur];           // final entities (d_out scratch)
  float* relhF = relhB[curRelh];

  // copy final entities into ws (logits reads F while writing out); 1.28M float4
  copy_vec4<<<5000, 256, 0, stream>>>(
      reinterpret_cast<const float4*>(entF), reinterpret_cast<float4*>(entWS),
      (int)(NEH / 4));

  // ConvTransE fronts: transpose weights, materialize Y, coalesced split-K GEMM
  transposeFW<<<2048, 256, 0, stream>>>(oc_fw, fwTo);
  transposeFW<<<2048, 256, 0, stream>>>(rc_fw, fwTr);

  conv_relu<<<NT / 8, 256, 0, stream>>>(entF, qsub, relhF, qrel, oc_k, oc_kb, Ybuf);
  conv_gemm<<<dim3(NT / 32, KSP), 256, 0, stream>>>(Ybuf, fwTo, Zp);
  conv_finalize<<<NT * H / 256, 256, 0, stream>>>(Zp, oc_fb, Zo);

  conv_relu<<<NT / 8, 256, 0, stream>>>(entF, qsub, entF, qobj, rc_k, rc_kb, Ybuf);
  conv_gemm<<<dim3(NT / 32, KSP), 256, 0, stream>>>(Ybuf, fwTr, Zp);
  conv_finalize<<<NT * H / 256, 256, 0, stream>>>(Zp, rc_fb, Zr);

  // logits (R5 gemm2; F from ws)
  logits_gemm2<<<dim3((NE + 127) / 128, NT / 128), 256, 0, stream>>>(Zo, entWS, out, NE);
  logits_gemm2<<<dim3(NR / 128, NT / 128), 256, 0, stream>>>(Zr, relhF, out + (size_t)NT * NE, NR);
}